// Round 4
// baseline (6682.832 us; speedup 1.0000x reference)
//
#include <hip/hip_runtime.h>
#include <hip/hip_fp16.h>

#define NN 100000      // nodes graph 1
#define MMn 200000     // nodes graph 2 (link nodes)
#define DD 64
#define NE1 3200000
#define NE2 3200000
#define SH 9           // staging bucket shift (512-node buckets)

static inline int cdiv_l(long a, long b) { return (int)((a + b - 1) / b); }

// ================= small utility kernels =================
__global__ void fill_i32_k(int* p, int v, long n) {
    long i = (long)blockIdx.x * blockDim.x + threadIdx.x;
    long st = (long)gridDim.x * blockDim.x;
    for (; i < n; i += st) p[i] = v;
}
__global__ void fill_f32_k(float* p, float v, long n) {
    long i = (long)blockIdx.x * blockDim.x + threadIdx.x;
    long st = (long)gridDim.x * blockDim.x;
    for (; i < n; i += st) p[i] = v;
}

// ================= histograms =================
__global__ void hist1_k(const int* __restrict__ col, int ne, int* __restrict__ cnt) {
    int i = blockIdx.x * blockDim.x + threadIdx.x;
    if (i < ne) atomicAdd(&cnt[col[i]], 1);
}
// one pass over edge2: count by col (fwd CSR) and by row (reverse CSR)
__global__ void hist2_k(const int* __restrict__ e2, int ne,
                        int* __restrict__ cntA, int* __restrict__ cntB) {
    int i = blockIdx.x * blockDim.x + threadIdx.x;
    if (i >= ne) return;
    int r = e2[i], c = e2[ne + i];
    atomicAdd(&cntA[c], 1);
    atomicAdd(&cntB[r], 1);
}
__global__ void histx_k(const int* __restrict__ x, int n, int* __restrict__ freq) {
    int i = blockIdx.x * blockDim.x + threadIdx.x;
    if (i < n) atomicAdd(&freq[x[i]], 1);
}
__global__ void dinv_from_cnt_k(const int* __restrict__ cnt, float* __restrict__ dinv, int n) {
    int i = blockIdx.x * blockDim.x + threadIdx.x;
    if (i < n) dinv[i] = rsqrtf((float)cnt[i] + 1.0f);
}

// ================= 2-level exclusive scan =================
__global__ __launch_bounds__(256) void scan_sums_k(const int* __restrict__ cnt, int n, int* __restrict__ bsum) {
    __shared__ int s[256];
    int b = blockIdx.x, t = threadIdx.x;
    int base = b * 1024 + t * 4;
    int T = 0;
#pragma unroll
    for (int j = 0; j < 4; ++j) { int i = base + j; if (i < n) T += cnt[i]; }
    s[t] = T; __syncthreads();
    for (int o = 128; o > 0; o >>= 1) { if (t < o) s[t] += s[t + o]; __syncthreads(); }
    if (t == 0) bsum[b] = s[0];
}
__global__ __launch_bounds__(256) void scan_tops_k(int* bsum, int nb) {
    __shared__ int s[256];
    int t = threadIdx.x;
    int v = (t < nb) ? bsum[t] : 0;
    s[t] = v; __syncthreads();
    for (int o = 1; o < 256; o <<= 1) {
        int x = (t >= o) ? s[t - o] : 0;
        __syncthreads();
        s[t] += x;
        __syncthreads();
    }
    if (t < nb) bsum[t] = s[t] - v;   // exclusive
}
__global__ __launch_bounds__(256) void scan_apply_k(const int* __restrict__ cnt, int n,
                                                    const int* __restrict__ bpre, int* __restrict__ off) {
    __shared__ int sT[256];
    int b = blockIdx.x, t = threadIdx.x;
    int base = b * 1024 + t * 4;
    int v[4]; int T = 0;
#pragma unroll
    for (int j = 0; j < 4; ++j) { int i = base + j; v[j] = (i < n) ? cnt[i] : 0; T += v[j]; }
    sT[t] = T; __syncthreads();
    for (int o = 1; o < 256; o <<= 1) {
        int x = (t >= o) ? sT[t - o] : 0;
        __syncthreads();
        sT[t] += x;
        __syncthreads();
    }
    int ex = sT[t] - T + bpre[b];
#pragma unroll
    for (int j = 0; j < 4; ++j) {
        int i = base + j;
        if (i < n) off[i] = ex;
        ex += v[j];
        if (i == n - 1) off[n] = ex;
    }
}

// ================= bucketed CSR fill =================
__global__ void bcur_init_k(const int* __restrict__ off, int nb, int* __restrict__ bcur) {
    int b = blockIdx.x * blockDim.x + threadIdx.x;
    if (b < nb) bcur[b] = off[b << SH];
}
// Pass A: append (val,key) into bucket-grouped staging. Per-bucket appends are
// address-consecutive -> L2 merges into full-line writes (no write-allocate waste).
__global__ void stage_k(const int* __restrict__ keys, const int* __restrict__ vals, int ne,
                        int* __restrict__ bcur, int2* __restrict__ stg) {
    int i = blockIdx.x * blockDim.x + threadIdx.x;
    if (i >= ne) return;
    int k = keys[i];
    int pos = atomicAdd(&bcur[k >> SH], 1);
    stg[pos] = make_int2(vals[i], k);
}
// Pass B: scatter within bucket-local rows region (64-128KB, L2-resident).
__global__ void fill_stage_k(const int2* __restrict__ stg, int ne,
                             const int* __restrict__ off, int* __restrict__ cnt,
                             int* __restrict__ rows) {
    int i = blockIdx.x * blockDim.x + threadIdx.x;
    if (i >= ne) return;
    int2 u = stg[i];
    int old = atomicSub(&cnt[u.y], 1);
    rows[off[u.y] + old - 1] = u.x;
}

// ================= GraphNorm coefficient (inline, per consumer) =================
__device__ __forceinline__ void gn_coef(const float* __restrict__ stats,
                                        const float* __restrict__ w, const float* __restrict__ b,
                                        const float* __restrict__ ms, float nrows, int d,
                                        float& sc, float& sh) {
    float mean = stats[d] / nrows;
    float ex2 = stats[64 + d] / nrows;
    float m = ms[d];
    float var = ex2 - mean * mean * (2.f * m - m * m);
    float is = rsqrtf(var + 1e-5f);
    sc = is * w[d];
    sh = b[d] - m * mean * sc;
}

// ================= embedding-table stats (frequency-weighted moments) =================
__global__ __launch_bounds__(256) void tabstats_k(const float* __restrict__ T, const int* __restrict__ freq,
                                                  int nv, float* __restrict__ stats) {
    __shared__ float sS[256], sQ[256];
    int tid = threadIdx.x; int d = tid & 63; int g = tid >> 6;
    float s = 0.f, q = 0.f;
    for (int v = g; v < nv; v += 4) {
        float f = (float)freq[v];
        float t = T[(long)v * DD + d];
        s += f * t; q += f * t * t;
    }
    sS[tid] = s; sQ[tid] = q; __syncthreads();
    if (tid < 128) { sS[tid] += sS[tid + 128]; sQ[tid] += sQ[tid + 128]; }
    __syncthreads();
    if (tid < 64) { stats[d] = sS[tid] + sS[tid + 64]; stats[64 + d] = sQ[tid] + sQ[tid + 64]; }
}

// ================= normalized fp16 embedding table =================
__global__ void tnorm_k(const float* __restrict__ T, const float* __restrict__ stats,
                        const float* __restrict__ w, const float* __restrict__ b,
                        const float* __restrict__ ms, __half* __restrict__ Tn, int nv) {
    int i = blockIdx.x * blockDim.x + threadIdx.x;
    if (i >= nv * DD) return;
    int d = i & 63;
    float sc, sh;
    gn_coef(stats, w, b, ms, (float)NN, d, sc, sh);
    Tn[i] = __float2half(fmaf(T[i], sc, sh));
}

// ================= column stats over fp16 matrix (sum, sumsq) =================
__global__ __launch_bounds__(256) void gn_stats_k(const __half2* __restrict__ xx, long nu,
                                                  float* __restrict__ stats) {
    __shared__ float s0[256], s1[256], q0[256], q1[256];
    int tid = threadIdx.x;
    float a0 = 0.f, a1 = 0.f, b0 = 0.f, b1 = 0.f;
    for (long i = (long)blockIdx.x * 256 + tid; i < nu; i += (long)gridDim.x * 256) {
        __half2 u = xx[i];
        float x0 = __low2float(u), x1 = __high2float(u);
        a0 += x0; b0 += x0 * x0;
        a1 += x1; b1 += x1 * x1;
    }
    s0[tid] = a0; s1[tid] = a1; q0[tid] = b0; q1[tid] = b1;
    __syncthreads();
    for (int o = 128; o >= 32; o >>= 1) {
        if (tid < o) { s0[tid] += s0[tid + o]; s1[tid] += s1[tid + o]; q0[tid] += q0[tid + o]; q1[tid] += q1[tid + o]; }
        __syncthreads();
    }
    if (tid < 32) {
        int d0 = 2 * tid;
        atomicAdd(&stats[d0], s0[tid]);
        atomicAdd(&stats[d0 + 1], s1[tid]);
        atomicAdd(&stats[64 + d0], q0[tid]);
        atomicAdd(&stats[64 + d0 + 1], q1[tid]);
    }
}

// ================= fused GCN layer: gather(+opt norm/relu on reads) + matmul + bias =================
// NORM: 0 = raw input, 1 = affine (GN, no relu), 2 = affine + relu
template <int NORM>
__global__ __launch_bounds__(256) void gcn_fused_k(
    const __half* __restrict__ hsrc, const int* __restrict__ off,
    const int* __restrict__ rows, const float* __restrict__ dinv,
    const float* __restrict__ stats, const float* __restrict__ gw,
    const float* __restrict__ gb, const float* __restrict__ gms, float nprev,
    const float* __restrict__ W, const float* __restrict__ bias,
    __half* __restrict__ Z, int n)
{
    __shared__ float sW[4096];
    __shared__ float sP[256];
    int tid = threadIdx.x;
    for (int i = tid; i < 4096; i += 256) sW[i] = W[i];
    int wr = tid >> 6, d = tid & 63;
    int node = blockIdx.x * 4 + wr;
    float sc = 1.f, sh = 0.f;
    if (NORM) gn_coef(stats, gw, gb, gms, nprev, d, sc, sh);
    float P = 0.f;
    if (node < n) {
        int s = off[node], e = off[node + 1];
        float dc = dinv[node];
        float x = __half2float(hsrc[(long)node * DD + d]);
        if (NORM) { x = fmaf(x, sc, sh); if (NORM == 2) x = fmaxf(x, 0.f); }
        float a0 = x * dc, a1 = 0.f, a2 = 0.f, a3 = 0.f;
        int i = s;
        for (; i + 3 < e; i += 4) {
            int r0 = rows[i], r1 = rows[i + 1], r2 = rows[i + 2], r3 = rows[i + 3];
            float x0 = __half2float(hsrc[(long)r0 * DD + d]);
            float x1 = __half2float(hsrc[(long)r1 * DD + d]);
            float x2 = __half2float(hsrc[(long)r2 * DD + d]);
            float x3 = __half2float(hsrc[(long)r3 * DD + d]);
            float w0 = dinv[r0], w1 = dinv[r1], w2 = dinv[r2], w3 = dinv[r3];
            if (NORM) {
                x0 = fmaf(x0, sc, sh); x1 = fmaf(x1, sc, sh);
                x2 = fmaf(x2, sc, sh); x3 = fmaf(x3, sc, sh);
                if (NORM == 2) {
                    x0 = fmaxf(x0, 0.f); x1 = fmaxf(x1, 0.f);
                    x2 = fmaxf(x2, 0.f); x3 = fmaxf(x3, 0.f);
                }
            }
            a0 = fmaf(x0, w0, a0); a1 = fmaf(x1, w1, a1);
            a2 = fmaf(x2, w2, a2); a3 = fmaf(x3, w3, a3);
        }
        for (; i < e; ++i) {
            int r = rows[i];
            float xx = __half2float(hsrc[(long)r * DD + d]);
            if (NORM) { xx = fmaf(xx, sc, sh); if (NORM == 2) xx = fmaxf(xx, 0.f); }
            a0 = fmaf(xx, dinv[r], a0);
        }
        P = ((a0 + a1) + (a2 + a3)) * dc;
    }
    sP[wr * 64 + d] = P;
    __syncthreads();
    float z = bias[d];
#pragma unroll
    for (int k = 0; k < 64; ++k) z = fmaf(sP[wr * 64 + k], sW[k * 64 + d], z);
    if (node < n) Z[(long)node * DD + d] = __float2half(z);
}

// ================= conv1-l0: gather directly from normalized fp16 table =================
__global__ __launch_bounds__(256) void gcn_tab_fused_k(
    const __half* __restrict__ Tn, const int* __restrict__ xidx,
    const int* __restrict__ off, const int* __restrict__ rows,
    const float* __restrict__ dinv,
    const float* __restrict__ W, const float* __restrict__ bias,
    __half* __restrict__ Z, int n)
{
    __shared__ float sW[4096];
    __shared__ float sP[256];
    int tid = threadIdx.x;
    for (int i = tid; i < 4096; i += 256) sW[i] = W[i];
    int wr = tid >> 6, d = tid & 63;
    int node = blockIdx.x * 4 + wr;
    float P = 0.f;
    if (node < n) {
        int s = off[node], e = off[node + 1];
        float dc = dinv[node];
        float a0 = __half2float(Tn[(long)xidx[node] * DD + d]) * dc;
        float a1 = 0.f, a2 = 0.f, a3 = 0.f;
        int i = s;
        for (; i + 3 < e; i += 4) {
            int r0 = rows[i], r1 = rows[i + 1], r2 = rows[i + 2], r3 = rows[i + 3];
            int x0 = xidx[r0], x1 = xidx[r1], x2 = xidx[r2], x3 = xidx[r3];
            float w0 = dinv[r0], w1 = dinv[r1], w2 = dinv[r2], w3 = dinv[r3];
            a0 = fmaf(__half2float(Tn[(long)x0 * DD + d]), w0, a0);
            a1 = fmaf(__half2float(Tn[(long)x1 * DD + d]), w1, a1);
            a2 = fmaf(__half2float(Tn[(long)x2 * DD + d]), w2, a2);
            a3 = fmaf(__half2float(Tn[(long)x3 * DD + d]), w3, a3);
        }
        for (; i < e; ++i) {
            int r = rows[i];
            a0 = fmaf(__half2float(Tn[(long)xidx[r] * DD + d]), dinv[r], a0);
        }
        P = ((a0 + a1) + (a2 + a3)) * dc;
    }
    sP[wr * 64 + d] = P;
    __syncthreads();
    float z = bias[d];
#pragma unroll
    for (int k = 0; k < 64; ++k) z = fmaf(sP[wr * 64 + k], sW[k * 64 + d], z);
    if (node < n) Z[(long)node * DD + d] = __float2half(z);
}

// ================= link-pair product with fused GN+relu on reads =================
__global__ __launch_bounds__(256) void pair_norm_mul_k(
    const __half* __restrict__ Z2, const int* __restrict__ pos,
    const float* __restrict__ stats, const float* __restrict__ gw,
    const float* __restrict__ gb, const float* __restrict__ gms,
    __half* __restrict__ h2)
{
    int tid = threadIdx.x, wr = tid >> 6, d = tid & 63;
    int idx = blockIdx.x * 4 + wr;
    if (idx >= MMn) return;
    float sc, sh;
    gn_coef(stats, gw, gb, gms, (float)NN, d, sc, sh);
    int p0 = pos[2 * idx], p1 = pos[2 * idx + 1];
    float v0 = fmaxf(fmaf(__half2float(Z2[(long)p0 * DD + d]), sc, sh), 0.f);
    float v1 = fmaxf(fmaf(__half2float(Z2[(long)p1 * DD + d]), sc, sh), 0.f);
    h2[(long)idx * DD + d] = __float2half(v0 * v1);
}

// ================= dual-branch GN+relu+add =================
__global__ __launch_bounds__(256) void dualadd_k(
    const __half2* __restrict__ Za, const __half2* __restrict__ Zb,
    const float* __restrict__ stA, const float* __restrict__ wA, const float* __restrict__ bA, const float* __restrict__ msA,
    const float* __restrict__ stB, const float* __restrict__ wB, const float* __restrict__ bB, const float* __restrict__ msB,
    __half2* __restrict__ hout)
{
    const long nu = (long)MMn * 32;
    int tid = threadIdx.x;
    int d0 = (2 * tid) & 63;
    float scA0, shA0, scA1, shA1, scB0, shB0, scB1, shB1;
    gn_coef(stA, wA, bA, msA, (float)MMn, d0, scA0, shA0);
    gn_coef(stA, wA, bA, msA, (float)MMn, d0 + 1, scA1, shA1);
    gn_coef(stB, wB, bB, msB, (float)MMn, d0, scB0, shB0);
    gn_coef(stB, wB, bB, msB, (float)MMn, d0 + 1, scB1, shB1);
    for (long i = (long)blockIdx.x * 256 + tid; i < nu; i += (long)gridDim.x * 256) {
        __half2 ua = Za[i], ub = Zb[i];
        float a0 = __low2float(ua), a1 = __high2float(ua);
        float c0 = __low2float(ub), c1 = __high2float(ub);
        float o0 = fmaxf(fmaf(a0, scA0, shA0), 0.f) + fmaxf(fmaf(c0, scB0, shB0), 0.f);
        float o1 = fmaxf(fmaf(a1, scA1, shA1), 0.f) + fmaxf(fmaf(c1, scB1, shB1), 0.f);
        hout[i] = __halves2half2(__float2half(o0), __float2half(o1));
    }
}

// ================= final: dual GN+relu+add on reads, pair product, dot predW =================
__global__ __launch_bounds__(256) void final_fused_k(
    const __half* __restrict__ Za, const __half* __restrict__ Zb,
    const int* __restrict__ pos2,
    const float* __restrict__ stA, const float* __restrict__ wA, const float* __restrict__ bA, const float* __restrict__ msA,
    const float* __restrict__ stB, const float* __restrict__ wB, const float* __restrict__ bB, const float* __restrict__ msB,
    const float* __restrict__ pw, const float* __restrict__ pb,
    float* __restrict__ out, int nout)
{
    int tid = threadIdx.x, wr = tid >> 6, d = tid & 63;
    int i = blockIdx.x * 4 + wr;
    if (i >= nout) return;
    float scA, shA, scB, shB;
    gn_coef(stA, wA, bA, msA, (float)MMn, d, scA, shA);
    gn_coef(stB, wB, bB, msB, (float)MMn, d, scB, shB);
    int p0 = pos2[2 * i], p1 = pos2[2 * i + 1];
    float v0 = fmaxf(fmaf(__half2float(Za[(long)p0 * DD + d]), scA, shA), 0.f)
             + fmaxf(fmaf(__half2float(Zb[(long)p0 * DD + d]), scB, shB), 0.f);
    float v1 = fmaxf(fmaf(__half2float(Za[(long)p1 * DD + d]), scA, shA), 0.f)
             + fmaxf(fmaf(__half2float(Zb[(long)p1 * DD + d]), scB, shB), 0.f);
    float v = v0 * v1 * pw[d];
#pragma unroll
    for (int o = 32; o > 0; o >>= 1) v += __shfl_down(v, o, 64);
    if (d == 0) out[i] = v + pb[0];
}

extern "C" void kernel_launch(void* const* d_in, const int* in_sizes, int n_in,
                              void* d_out, int out_size, void* d_ws, size_t ws_size,
                              hipStream_t stream) {
    const int* x      = (const int*)d_in[0];
    const int* edge1  = (const int*)d_in[2];
    const int* edge2  = (const int*)d_in[3];
    const int* pos1   = (const int*)d_in[5];
    const int* pos2   = (const int*)d_in[6];
    const float* emb  = (const float*)d_in[7];
    const float* egw  = (const float*)d_in[8];
    const float* egb  = (const float*)d_in[9];
    const float* egm  = (const float*)d_in[10];
    const float* c1W  = (const float*)d_in[11];
    const float* c1b  = (const float*)d_in[12];
    const float* c1gw = (const float*)d_in[13];
    const float* c1gb = (const float*)d_in[14];
    const float* c1gm = (const float*)d_in[15];
    const float* c2W  = (const float*)d_in[16];
    const float* c2b  = (const float*)d_in[17];
    const float* c2gw = (const float*)d_in[18];
    const float* c2gb = (const float*)d_in[19];
    const float* c2gm = (const float*)d_in[20];
    const float* c2rW  = (const float*)d_in[21];
    const float* c2rb  = (const float*)d_in[22];
    const float* c2rgw = (const float*)d_in[23];
    const float* c2rgb = (const float*)d_in[24];
    const float* c2rgm = (const float*)d_in[25];
    const float* predW = (const float*)d_in[26];
    const float* predb = (const float*)d_in[27];
    float* out = (float*)d_out;
    const int NV = 1001;   // emb table rows (MAXX+1)

    // ---- workspace layout ----
    char* p = (char*)d_ws;
    const long SZH = (long)MMn * DD;  // elements per fp16 node buffer
    __half* BA = (__half*)p; p += SZH * 2;
    __half* BB = (__half*)p; p += SZH * 2;
    __half* BC = (__half*)p; p += SZH * 2;
    int2* stg  = (int2*)p;  p += (long)NE2 * 8;
    int* cnt1 = (int*)p; p += (long)NN * 4;
    int* cntA = (int*)p; p += (long)MMn * 4;
    int* cntB = (int*)p; p += (long)MMn * 4;
    int* freq = (int*)p; p += 1024 * 4;          // zeroed together with cnt*
    float* dinv1  = (float*)p; p += (long)NN * 4;
    float* dinv2  = (float*)p; p += (long)MMn * 4;
    float* dinv2r = (float*)p; p += (long)MMn * 4;
    int* off1 = (int*)p; p += (long)(NN + 8) * 4;
    int* offA = (int*)p; p += (long)(MMn + 8) * 4;
    int* offB = (int*)p; p += (long)(MMn + 8) * 4;
    int* rows1 = (int*)p; p += (long)NE1 * 4;
    int* rowsA = (int*)p; p += (long)NE2 * 4;
    int* rowsB = (int*)p; p += (long)NE2 * 4;
    int* scanb = (int*)p; p += 256 * 4;
    int* bcur  = (int*)p; p += 512 * 4;
    float* stats = (float*)p; p += 7 * 128 * 4;   // slots 0..6
    __half* Tn = (__half*)p; p += (long)NV * DD * 2;
    if ((size_t)(p - (char*)d_ws) > ws_size) return;

    const int nb1 = cdiv_l(NN, 1 << SH);    // 196 staging buckets
    const int nb2 = cdiv_l(MMn, 1 << SH);   // 391
    const int sc1 = cdiv_l(NN, 1024), sc2 = cdiv_l(MMn, 1024);  // scan blocks

    // ---- zero counters (cnt1,cntA,cntB,freq contiguous) + stats ----
    fill_i32_k<<<1024, 256, 0, stream>>>(cnt1, 0, (long)(NN + 2 * MMn + 1024));
    fill_f32_k<<<1, 256, 0, stream>>>(stats, 0.f, 7 * 128);

    // ---- histograms + dinv ----
    hist1_k<<<cdiv_l(NE1, 256), 256, 0, stream>>>(edge1 + NE1, NE1, cnt1);
    hist2_k<<<cdiv_l(NE2, 256), 256, 0, stream>>>(edge2, NE2, cntA, cntB);
    histx_k<<<cdiv_l(NN, 256), 256, 0, stream>>>(x, NN, freq);
    dinv_from_cnt_k<<<cdiv_l(NN + 2 * MMn, 256), 256, 0, stream>>>(cnt1, dinv1, NN + 2 * MMn);

    // ---- scans ----
    scan_sums_k<<<sc1, 256, 0, stream>>>(cnt1, NN, scanb);
    scan_tops_k<<<1, 256, 0, stream>>>(scanb, sc1);
    scan_apply_k<<<sc1, 256, 0, stream>>>(cnt1, NN, scanb, off1);
    scan_sums_k<<<sc2, 256, 0, stream>>>(cntA, MMn, scanb);
    scan_tops_k<<<1, 256, 0, stream>>>(scanb, sc2);
    scan_apply_k<<<sc2, 256, 0, stream>>>(cntA, MMn, scanb, offA);
    scan_sums_k<<<sc2, 256, 0, stream>>>(cntB, MMn, scanb);
    scan_tops_k<<<1, 256, 0, stream>>>(scanb, sc2);
    scan_apply_k<<<sc2, 256, 0, stream>>>(cntB, MMn, scanb, offB);

    // ---- emb stats + normalized fp16 table ----
    tabstats_k<<<1, 256, 0, stream>>>(emb, freq, NV, stats);
    tnorm_k<<<cdiv_l((long)NV * DD, 256), 256, 0, stream>>>(emb, stats, egw, egb, egm, Tn, NV);

    // ---- bucketed CSR fills (one staging buffer, serialized on stream) ----
    bcur_init_k<<<cdiv_l(nb1, 256), 256, 0, stream>>>(off1, nb1, bcur);
    stage_k<<<cdiv_l(NE1, 256), 256, 0, stream>>>(edge1 + NE1, edge1, NE1, bcur, stg);
    fill_stage_k<<<cdiv_l(NE1, 256), 256, 0, stream>>>(stg, NE1, off1, cnt1, rows1);
    bcur_init_k<<<cdiv_l(nb2, 256), 256, 0, stream>>>(offA, nb2, bcur);
    stage_k<<<cdiv_l(NE2, 256), 256, 0, stream>>>(edge2 + NE2, edge2, NE2, bcur, stg);
    fill_stage_k<<<cdiv_l(NE2, 256), 256, 0, stream>>>(stg, NE2, offA, cntA, rowsA);
    bcur_init_k<<<cdiv_l(nb2, 256), 256, 0, stream>>>(offB, nb2, bcur);
    stage_k<<<cdiv_l(NE2, 256), 256, 0, stream>>>(edge2, edge2 + NE2, NE2, bcur, stg);
    fill_stage_k<<<cdiv_l(NE2, 256), 256, 0, stream>>>(stg, NE2, offB, cntB, rowsB);

    // ---- conv1 l0: table-gather + mm -> BB, stats slot1 ----
    gcn_tab_fused_k<<<cdiv_l(NN, 4), 256, 0, stream>>>(Tn, x, off1, rows1, dinv1, c1W, c1b, BB, NN);
    gn_stats_k<<<1024, 256, 0, stream>>>((const __half2*)BB, (long)NN * 32, stats + 128);

    // ---- conv1 l1: gather(norm+relu) + mm -> BA, stats slot2 ----
    gcn_fused_k<2><<<cdiv_l(NN, 4), 256, 0, stream>>>(BB, off1, rows1, dinv1,
        stats + 128, c1gw, c1gb, c1gm, (float)NN, c1W + 4096, c1b + 64, BA, NN);
    gn_stats_k<<<1024, 256, 0, stream>>>((const __half2*)BA, (long)NN * 32, stats + 256);

    // ---- pair product (norm+relu fused on reads) -> BC ----
    pair_norm_mul_k<<<cdiv_l(MMn, 4), 256, 0, stream>>>(BA, pos1,
        stats + 256, c1gw + 64, c1gb + 64, c1gm + 64, BC);

    // ---- conv2 l0 ----
    gcn_fused_k<0><<<cdiv_l(MMn, 4), 256, 0, stream>>>(BC, offA, rowsA, dinv2,
        stats, nullptr, nullptr, nullptr, 1.f, c2W, c2b, BB, MMn);
    gn_stats_k<<<1024, 256, 0, stream>>>((const __half2*)BB, (long)MMn * 32, stats + 384);
    gcn_fused_k<0><<<cdiv_l(MMn, 4), 256, 0, stream>>>(BC, offB, rowsB, dinv2r,
        stats, nullptr, nullptr, nullptr, 1.f, c2rW, c2rb, BA, MMn);
    gn_stats_k<<<1024, 256, 0, stream>>>((const __half2*)BA, (long)MMn * 32, stats + 512);
    dualadd_k<<<1024, 256, 0, stream>>>((const __half2*)BB, (const __half2*)BA,
        stats + 384, c2gw, c2gb, c2gm,
        stats + 512, c2rgw, c2rgb, c2rgm, (__half2*)BC);

    // ---- conv2 l1 ----
    gcn_fused_k<0><<<cdiv_l(MMn, 4), 256, 0, stream>>>(BC, offA, rowsA, dinv2,
        stats, nullptr, nullptr, nullptr, 1.f, c2W + 4096, c2b + 64, BB, MMn);
    gn_stats_k<<<1024, 256, 0, stream>>>((const __half2*)BB, (long)MMn * 32, stats + 640);
    gcn_fused_k<0><<<cdiv_l(MMn, 4), 256, 0, stream>>>(BC, offB, rowsB, dinv2r,
        stats, nullptr, nullptr, nullptr, 1.f, c2rW + 4096, c2rb + 64, BA, MMn);
    gn_stats_k<<<1024, 256, 0, stream>>>((const __half2*)BA, (long)MMn * 32, stats + 768);

    // ---- final ----
    final_fused_k<<<cdiv_l(out_size, 4), 256, 0, stream>>>(BB, BA, pos2,
        stats + 640, c2gw + 64, c2gb + 64, c2gm + 64,
        stats + 768, c2rgw + 64, c2rgb + 64, c2rgm + 64,
        predW, predb, out, out_size);
}

// Round 5
// 3171.317 us; speedup vs baseline: 2.1073x; 2.1073x over previous
//
#include <hip/hip_runtime.h>
#include <hip/hip_fp16.h>

#define NN 100000      // nodes graph 1
#define MMn 200000     // nodes graph 2 (link nodes)
#define DD 64
#define NE1 3200000
#define NE2 3200000
#define SH 4           // staging bucket shift (16-node buckets; SH=9 caused 8000-deep atomic chains)

static inline int cdiv_l(long a, long b) { return (int)((a + b - 1) / b); }

// ================= small utility kernels =================
__global__ void fill_i32_k(int* p, int v, long n) {
    long i = (long)blockIdx.x * blockDim.x + threadIdx.x;
    long st = (long)gridDim.x * blockDim.x;
    for (; i < n; i += st) p[i] = v;
}
__global__ void fill_f32_k(float* p, float v, long n) {
    long i = (long)blockIdx.x * blockDim.x + threadIdx.x;
    long st = (long)gridDim.x * blockDim.x;
    for (; i < n; i += st) p[i] = v;
}

// ================= histograms =================
__global__ void hist1_k(const int* __restrict__ col, int ne, int* __restrict__ cnt) {
    int i = blockIdx.x * blockDim.x + threadIdx.x;
    if (i < ne) atomicAdd(&cnt[col[i]], 1);
}
// one pass over edge2: count by col (fwd CSR) and by row (reverse CSR)
__global__ void hist2_k(const int* __restrict__ e2, int ne,
                        int* __restrict__ cntA, int* __restrict__ cntB) {
    int i = blockIdx.x * blockDim.x + threadIdx.x;
    if (i >= ne) return;
    int r = e2[i], c = e2[ne + i];
    atomicAdd(&cntA[c], 1);
    atomicAdd(&cntB[r], 1);
}
__global__ void histx_k(const int* __restrict__ x, int n, int* __restrict__ freq) {
    int i = blockIdx.x * blockDim.x + threadIdx.x;
    if (i < n) atomicAdd(&freq[x[i]], 1);
}
__global__ void dinv_from_cnt_k(const int* __restrict__ cnt, float* __restrict__ dinv, int n) {
    int i = blockIdx.x * blockDim.x + threadIdx.x;
    if (i < n) dinv[i] = rsqrtf((float)cnt[i] + 1.0f);
}

// ================= 2-level exclusive scan =================
__global__ __launch_bounds__(256) void scan_sums_k(const int* __restrict__ cnt, int n, int* __restrict__ bsum) {
    __shared__ int s[256];
    int b = blockIdx.x, t = threadIdx.x;
    int base = b * 1024 + t * 4;
    int T = 0;
#pragma unroll
    for (int j = 0; j < 4; ++j) { int i = base + j; if (i < n) T += cnt[i]; }
    s[t] = T; __syncthreads();
    for (int o = 128; o > 0; o >>= 1) { if (t < o) s[t] += s[t + o]; __syncthreads(); }
    if (t == 0) bsum[b] = s[0];
}
__global__ __launch_bounds__(256) void scan_tops_k(int* bsum, int nb) {
    __shared__ int s[256];
    int t = threadIdx.x;
    int v = (t < nb) ? bsum[t] : 0;
    s[t] = v; __syncthreads();
    for (int o = 1; o < 256; o <<= 1) {
        int x = (t >= o) ? s[t - o] : 0;
        __syncthreads();
        s[t] += x;
        __syncthreads();
    }
    if (t < nb) bsum[t] = s[t] - v;   // exclusive
}
__global__ __launch_bounds__(256) void scan_apply_k(const int* __restrict__ cnt, int n,
                                                    const int* __restrict__ bpre, int* __restrict__ off) {
    __shared__ int sT[256];
    int b = blockIdx.x, t = threadIdx.x;
    int base = b * 1024 + t * 4;
    int v[4]; int T = 0;
#pragma unroll
    for (int j = 0; j < 4; ++j) { int i = base + j; v[j] = (i < n) ? cnt[i] : 0; T += v[j]; }
    sT[t] = T; __syncthreads();
    for (int o = 1; o < 256; o <<= 1) {
        int x = (t >= o) ? sT[t - o] : 0;
        __syncthreads();
        sT[t] += x;
        __syncthreads();
    }
    int ex = sT[t] - T + bpre[b];
#pragma unroll
    for (int j = 0; j < 4; ++j) {
        int i = base + j;
        if (i < n) off[i] = ex;
        ex += v[j];
        if (i == n - 1) off[n] = ex;
    }
}

// ================= bucketed CSR fill =================
__global__ void bcur_init_k(const int* __restrict__ off, int nb, int* __restrict__ bcur) {
    int b = blockIdx.x * blockDim.x + threadIdx.x;
    if (b < nb) bcur[b] = off[(long)b << SH];
}
// Pass A: append (val,key) into bucket-grouped staging. Per-bucket appends are
// address-consecutive -> L2 merges into full-line writes. 16-node buckets keep
// per-cursor atomic chains ~256 deep (SH=9's ~8000 was the round-4 disaster).
__global__ void stage_k(const int* __restrict__ keys, const int* __restrict__ vals, int ne,
                        int* __restrict__ bcur, int2* __restrict__ stg) {
    int i = blockIdx.x * blockDim.x + threadIdx.x;
    if (i >= ne) return;
    int k = keys[i];
    int pos = atomicAdd(&bcur[k >> SH], 1);
    stg[pos] = make_int2(vals[i], k);
}
// Pass B: scatter within bucket-local rows region (~4KB, L2-resident).
__global__ void fill_stage_k(const int2* __restrict__ stg, int ne,
                             const int* __restrict__ off, int* __restrict__ cnt,
                             int* __restrict__ rows) {
    int i = blockIdx.x * blockDim.x + threadIdx.x;
    if (i >= ne) return;
    int2 u = stg[i];
    int old = atomicSub(&cnt[u.y], 1);
    rows[off[u.y] + old - 1] = u.x;
}

// ================= GraphNorm coefficient (inline, per consumer) =================
__device__ __forceinline__ void gn_coef(const float* __restrict__ stats,
                                        const float* __restrict__ w, const float* __restrict__ b,
                                        const float* __restrict__ ms, float nrows, int d,
                                        float& sc, float& sh) {
    float mean = stats[d] / nrows;
    float ex2 = stats[64 + d] / nrows;
    float m = ms[d];
    float var = ex2 - mean * mean * (2.f * m - m * m);
    float is = rsqrtf(var + 1e-5f);
    sc = is * w[d];
    sh = b[d] - m * mean * sc;
}

// ================= embedding-table stats (frequency-weighted moments) =================
__global__ __launch_bounds__(256) void tabstats_k(const float* __restrict__ T, const int* __restrict__ freq,
                                                  int nv, float* __restrict__ stats) {
    __shared__ float sS[256], sQ[256];
    int tid = threadIdx.x; int d = tid & 63; int g = tid >> 6;
    float s = 0.f, q = 0.f;
    for (int v = g; v < nv; v += 4) {
        float f = (float)freq[v];
        float t = T[(long)v * DD + d];
        s += f * t; q += f * t * t;
    }
    sS[tid] = s; sQ[tid] = q; __syncthreads();
    if (tid < 128) { sS[tid] += sS[tid + 128]; sQ[tid] += sQ[tid + 128]; }
    __syncthreads();
    if (tid < 64) { stats[d] = sS[tid] + sS[tid + 64]; stats[64 + d] = sQ[tid] + sQ[tid + 64]; }
}

// ================= normalized fp16 embedding table =================
__global__ void tnorm_k(const float* __restrict__ T, const float* __restrict__ stats,
                        const float* __restrict__ w, const float* __restrict__ b,
                        const float* __restrict__ ms, __half* __restrict__ Tn, int nv) {
    int i = blockIdx.x * blockDim.x + threadIdx.x;
    if (i >= nv * DD) return;
    int d = i & 63;
    float sc, sh;
    gn_coef(stats, w, b, ms, (float)NN, d, sc, sh);
    Tn[i] = __float2half(fmaf(T[i], sc, sh));
}

// ================= column stats over fp16 matrix (sum, sumsq) =================
__global__ __launch_bounds__(256) void gn_stats_k(const __half2* __restrict__ xx, long nu,
                                                  float* __restrict__ stats) {
    __shared__ float s0[256], s1[256], q0[256], q1[256];
    int tid = threadIdx.x;
    float a0 = 0.f, a1 = 0.f, b0 = 0.f, b1 = 0.f;
    for (long i = (long)blockIdx.x * 256 + tid; i < nu; i += (long)gridDim.x * 256) {
        __half2 u = xx[i];
        float x0 = __low2float(u), x1 = __high2float(u);
        a0 += x0; b0 += x0 * x0;
        a1 += x1; b1 += x1 * x1;
    }
    s0[tid] = a0; s1[tid] = a1; q0[tid] = b0; q1[tid] = b1;
    __syncthreads();
    for (int o = 128; o >= 32; o >>= 1) {
        if (tid < o) { s0[tid] += s0[tid + o]; s1[tid] += s1[tid + o]; q0[tid] += q0[tid + o]; q1[tid] += q1[tid + o]; }
        __syncthreads();
    }
    if (tid < 32) {
        int d0 = 2 * tid;
        atomicAdd(&stats[d0], s0[tid]);
        atomicAdd(&stats[d0 + 1], s1[tid]);
        atomicAdd(&stats[64 + d0], q0[tid]);
        atomicAdd(&stats[64 + d0 + 1], q1[tid]);
    }
}

// ================= fused GCN layer: gather(+opt norm/relu on reads) + matmul + bias =================
// NORM: 0 = raw input, 1 = affine (GN, no relu), 2 = affine + relu
template <int NORM>
__global__ __launch_bounds__(256) void gcn_fused_k(
    const __half* __restrict__ hsrc, const int* __restrict__ off,
    const int* __restrict__ rows, const float* __restrict__ dinv,
    const float* __restrict__ stats, const float* __restrict__ gw,
    const float* __restrict__ gb, const float* __restrict__ gms, float nprev,
    const float* __restrict__ W, const float* __restrict__ bias,
    __half* __restrict__ Z, int n)
{
    __shared__ float sW[4096];
    __shared__ float sP[256];
    int tid = threadIdx.x;
    for (int i = tid; i < 4096; i += 256) sW[i] = W[i];
    int wr = tid >> 6, d = tid & 63;
    int node = blockIdx.x * 4 + wr;
    float sc = 1.f, sh = 0.f;
    if (NORM) gn_coef(stats, gw, gb, gms, nprev, d, sc, sh);
    float P = 0.f;
    if (node < n) {
        int s = off[node], e = off[node + 1];
        float dc = dinv[node];
        float x = __half2float(hsrc[(long)node * DD + d]);
        if (NORM) { x = fmaf(x, sc, sh); if (NORM == 2) x = fmaxf(x, 0.f); }
        float a0 = x * dc, a1 = 0.f, a2 = 0.f, a3 = 0.f;
        int i = s;
        for (; i + 3 < e; i += 4) {
            int r0 = rows[i], r1 = rows[i + 1], r2 = rows[i + 2], r3 = rows[i + 3];
            float x0 = __half2float(hsrc[(long)r0 * DD + d]);
            float x1 = __half2float(hsrc[(long)r1 * DD + d]);
            float x2 = __half2float(hsrc[(long)r2 * DD + d]);
            float x3 = __half2float(hsrc[(long)r3 * DD + d]);
            float w0 = dinv[r0], w1 = dinv[r1], w2 = dinv[r2], w3 = dinv[r3];
            if (NORM) {
                x0 = fmaf(x0, sc, sh); x1 = fmaf(x1, sc, sh);
                x2 = fmaf(x2, sc, sh); x3 = fmaf(x3, sc, sh);
                if (NORM == 2) {
                    x0 = fmaxf(x0, 0.f); x1 = fmaxf(x1, 0.f);
                    x2 = fmaxf(x2, 0.f); x3 = fmaxf(x3, 0.f);
                }
            }
            a0 = fmaf(x0, w0, a0); a1 = fmaf(x1, w1, a1);
            a2 = fmaf(x2, w2, a2); a3 = fmaf(x3, w3, a3);
        }
        for (; i < e; ++i) {
            int r = rows[i];
            float xx = __half2float(hsrc[(long)r * DD + d]);
            if (NORM) { xx = fmaf(xx, sc, sh); if (NORM == 2) xx = fmaxf(xx, 0.f); }
            a0 = fmaf(xx, dinv[r], a0);
        }
        P = ((a0 + a1) + (a2 + a3)) * dc;
    }
    sP[wr * 64 + d] = P;
    __syncthreads();
    float z = bias[d];
#pragma unroll
    for (int k = 0; k < 64; ++k) z = fmaf(sP[wr * 64 + k], sW[k * 64 + d], z);
    if (node < n) Z[(long)node * DD + d] = __float2half(z);
}

// ================= conv1-l0: gather directly from normalized fp16 table =================
__global__ __launch_bounds__(256) void gcn_tab_fused_k(
    const __half* __restrict__ Tn, const int* __restrict__ xidx,
    const int* __restrict__ off, const int* __restrict__ rows,
    const float* __restrict__ dinv,
    const float* __restrict__ W, const float* __restrict__ bias,
    __half* __restrict__ Z, int n)
{
    __shared__ float sW[4096];
    __shared__ float sP[256];
    int tid = threadIdx.x;
    for (int i = tid; i < 4096; i += 256) sW[i] = W[i];
    int wr = tid >> 6, d = tid & 63;
    int node = blockIdx.x * 4 + wr;
    float P = 0.f;
    if (node < n) {
        int s = off[node], e = off[node + 1];
        float dc = dinv[node];
        float a0 = __half2float(Tn[(long)xidx[node] * DD + d]) * dc;
        float a1 = 0.f, a2 = 0.f, a3 = 0.f;
        int i = s;
        for (; i + 3 < e; i += 4) {
            int r0 = rows[i], r1 = rows[i + 1], r2 = rows[i + 2], r3 = rows[i + 3];
            int x0 = xidx[r0], x1 = xidx[r1], x2 = xidx[r2], x3 = xidx[r3];
            float w0 = dinv[r0], w1 = dinv[r1], w2 = dinv[r2], w3 = dinv[r3];
            a0 = fmaf(__half2float(Tn[(long)x0 * DD + d]), w0, a0);
            a1 = fmaf(__half2float(Tn[(long)x1 * DD + d]), w1, a1);
            a2 = fmaf(__half2float(Tn[(long)x2 * DD + d]), w2, a2);
            a3 = fmaf(__half2float(Tn[(long)x3 * DD + d]), w3, a3);
        }
        for (; i < e; ++i) {
            int r = rows[i];
            a0 = fmaf(__half2float(Tn[(long)xidx[r] * DD + d]), dinv[r], a0);
        }
        P = ((a0 + a1) + (a2 + a3)) * dc;
    }
    sP[wr * 64 + d] = P;
    __syncthreads();
    float z = bias[d];
#pragma unroll
    for (int k = 0; k < 64; ++k) z = fmaf(sP[wr * 64 + k], sW[k * 64 + d], z);
    if (node < n) Z[(long)node * DD + d] = __float2half(z);
}

// ================= link-pair product with fused GN+relu on reads =================
__global__ __launch_bounds__(256) void pair_norm_mul_k(
    const __half* __restrict__ Z2, const int* __restrict__ pos,
    const float* __restrict__ stats, const float* __restrict__ gw,
    const float* __restrict__ gb, const float* __restrict__ gms,
    __half* __restrict__ h2)
{
    int tid = threadIdx.x, wr = tid >> 6, d = tid & 63;
    int idx = blockIdx.x * 4 + wr;
    if (idx >= MMn) return;
    float sc, sh;
    gn_coef(stats, gw, gb, gms, (float)NN, d, sc, sh);
    int p0 = pos[2 * idx], p1 = pos[2 * idx + 1];
    float v0 = fmaxf(fmaf(__half2float(Z2[(long)p0 * DD + d]), sc, sh), 0.f);
    float v1 = fmaxf(fmaf(__half2float(Z2[(long)p1 * DD + d]), sc, sh), 0.f);
    h2[(long)idx * DD + d] = __float2half(v0 * v1);
}

// ================= dual-branch GN+relu+add =================
__global__ __launch_bounds__(256) void dualadd_k(
    const __half2* __restrict__ Za, const __half2* __restrict__ Zb,
    const float* __restrict__ stA, const float* __restrict__ wA, const float* __restrict__ bA, const float* __restrict__ msA,
    const float* __restrict__ stB, const float* __restrict__ wB, const float* __restrict__ bB, const float* __restrict__ msB,
    __half2* __restrict__ hout)
{
    const long nu = (long)MMn * 32;
    int tid = threadIdx.x;
    int d0 = (2 * tid) & 63;
    float scA0, shA0, scA1, shA1, scB0, shB0, scB1, shB1;
    gn_coef(stA, wA, bA, msA, (float)MMn, d0, scA0, shA0);
    gn_coef(stA, wA, bA, msA, (float)MMn, d0 + 1, scA1, shA1);
    gn_coef(stB, wB, bB, msB, (float)MMn, d0, scB0, shB0);
    gn_coef(stB, wB, bB, msB, (float)MMn, d0 + 1, scB1, shB1);
    for (long i = (long)blockIdx.x * 256 + tid; i < nu; i += (long)gridDim.x * 256) {
        __half2 ua = Za[i], ub = Zb[i];
        float a0 = __low2float(ua), a1 = __high2float(ua);
        float c0 = __low2float(ub), c1 = __high2float(ub);
        float o0 = fmaxf(fmaf(a0, scA0, shA0), 0.f) + fmaxf(fmaf(c0, scB0, shB0), 0.f);
        float o1 = fmaxf(fmaf(a1, scA1, shA1), 0.f) + fmaxf(fmaf(c1, scB1, shB1), 0.f);
        hout[i] = __halves2half2(__float2half(o0), __float2half(o1));
    }
}

// ================= final: dual GN+relu+add on reads, pair product, dot predW =================
__global__ __launch_bounds__(256) void final_fused_k(
    const __half* __restrict__ Za, const __half* __restrict__ Zb,
    const int* __restrict__ pos2,
    const float* __restrict__ stA, const float* __restrict__ wA, const float* __restrict__ bA, const float* __restrict__ msA,
    const float* __restrict__ stB, const float* __restrict__ wB, const float* __restrict__ bB, const float* __restrict__ msB,
    const float* __restrict__ pw, const float* __restrict__ pb,
    float* __restrict__ out, int nout)
{
    int tid = threadIdx.x, wr = tid >> 6, d = tid & 63;
    int i = blockIdx.x * 4 + wr;
    if (i >= nout) return;
    float scA, shA, scB, shB;
    gn_coef(stA, wA, bA, msA, (float)MMn, d, scA, shA);
    gn_coef(stB, wB, bB, msB, (float)MMn, d, scB, shB);
    int p0 = pos2[2 * i], p1 = pos2[2 * i + 1];
    float v0 = fmaxf(fmaf(__half2float(Za[(long)p0 * DD + d]), scA, shA), 0.f)
             + fmaxf(fmaf(__half2float(Zb[(long)p0 * DD + d]), scB, shB), 0.f);
    float v1 = fmaxf(fmaf(__half2float(Za[(long)p1 * DD + d]), scA, shA), 0.f)
             + fmaxf(fmaf(__half2float(Zb[(long)p1 * DD + d]), scB, shB), 0.f);
    float v = v0 * v1 * pw[d];
#pragma unroll
    for (int o = 32; o > 0; o >>= 1) v += __shfl_down(v, o, 64);
    if (d == 0) out[i] = v + pb[0];
}

extern "C" void kernel_launch(void* const* d_in, const int* in_sizes, int n_in,
                              void* d_out, int out_size, void* d_ws, size_t ws_size,
                              hipStream_t stream) {
    const int* x      = (const int*)d_in[0];
    const int* edge1  = (const int*)d_in[2];
    const int* edge2  = (const int*)d_in[3];
    const int* pos1   = (const int*)d_in[5];
    const int* pos2   = (const int*)d_in[6];
    const float* emb  = (const float*)d_in[7];
    const float* egw  = (const float*)d_in[8];
    const float* egb  = (const float*)d_in[9];
    const float* egm  = (const float*)d_in[10];
    const float* c1W  = (const float*)d_in[11];
    const float* c1b  = (const float*)d_in[12];
    const float* c1gw = (const float*)d_in[13];
    const float* c1gb = (const float*)d_in[14];
    const float* c1gm = (const float*)d_in[15];
    const float* c2W  = (const float*)d_in[16];
    const float* c2b  = (const float*)d_in[17];
    const float* c2gw = (const float*)d_in[18];
    const float* c2gb = (const float*)d_in[19];
    const float* c2gm = (const float*)d_in[20];
    const float* c2rW  = (const float*)d_in[21];
    const float* c2rb  = (const float*)d_in[22];
    const float* c2rgw = (const float*)d_in[23];
    const float* c2rgb = (const float*)d_in[24];
    const float* c2rgm = (const float*)d_in[25];
    const float* predW = (const float*)d_in[26];
    const float* predb = (const float*)d_in[27];
    float* out = (float*)d_out;
    const int NV = 1001;   // emb table rows (MAXX+1)

    // ---- workspace layout ----
    char* p = (char*)d_ws;
    const long SZH = (long)MMn * DD;  // elements per fp16 node buffer
    __half* BA = (__half*)p; p += SZH * 2;
    __half* BB = (__half*)p; p += SZH * 2;
    __half* BC = (__half*)p; p += SZH * 2;
    int2* stg  = (int2*)p;  p += (long)NE2 * 8;
    int* cnt1 = (int*)p; p += (long)NN * 4;
    int* cntA = (int*)p; p += (long)MMn * 4;
    int* cntB = (int*)p; p += (long)MMn * 4;
    int* freq = (int*)p; p += 1024 * 4;          // zeroed together with cnt*
    float* dinv1  = (float*)p; p += (long)NN * 4;
    float* dinv2  = (float*)p; p += (long)MMn * 4;
    float* dinv2r = (float*)p; p += (long)MMn * 4;
    int* off1 = (int*)p; p += (long)(NN + 8) * 4;
    int* offA = (int*)p; p += (long)(MMn + 8) * 4;
    int* offB = (int*)p; p += (long)(MMn + 8) * 4;
    int* rows1 = (int*)p; p += (long)NE1 * 4;
    int* rowsA = (int*)p; p += (long)NE2 * 4;
    int* rowsB = (int*)p; p += (long)NE2 * 4;
    int* scanb = (int*)p; p += 256 * 4;
    int* bcur  = (int*)p; p += 16384 * 4;         // up to 12500 bucket cursors at SH=4
    float* stats = (float*)p; p += 7 * 128 * 4;   // slots 0..6
    __half* Tn = (__half*)p; p += (long)NV * DD * 2;
    if ((size_t)(p - (char*)d_ws) > ws_size) return;

    const int nb1 = cdiv_l(NN, 1 << SH);    // 6250 staging buckets
    const int nb2 = cdiv_l(MMn, 1 << SH);   // 12500
    const int sc1 = cdiv_l(NN, 1024), sc2 = cdiv_l(MMn, 1024);  // scan blocks

    // ---- zero counters (cnt1,cntA,cntB,freq contiguous) + stats ----
    fill_i32_k<<<1024, 256, 0, stream>>>(cnt1, 0, (long)(NN + 2 * MMn + 1024));
    fill_f32_k<<<1, 256, 0, stream>>>(stats, 0.f, 7 * 128);

    // ---- histograms + dinv ----
    hist1_k<<<cdiv_l(NE1, 256), 256, 0, stream>>>(edge1 + NE1, NE1, cnt1);
    hist2_k<<<cdiv_l(NE2, 256), 256, 0, stream>>>(edge2, NE2, cntA, cntB);
    histx_k<<<cdiv_l(NN, 256), 256, 0, stream>>>(x, NN, freq);
    dinv_from_cnt_k<<<cdiv_l(NN + 2 * MMn, 256), 256, 0, stream>>>(cnt1, dinv1, NN + 2 * MMn);

    // ---- scans ----
    scan_sums_k<<<sc1, 256, 0, stream>>>(cnt1, NN, scanb);
    scan_tops_k<<<1, 256, 0, stream>>>(scanb, sc1);
    scan_apply_k<<<sc1, 256, 0, stream>>>(cnt1, NN, scanb, off1);
    scan_sums_k<<<sc2, 256, 0, stream>>>(cntA, MMn, scanb);
    scan_tops_k<<<1, 256, 0, stream>>>(scanb, sc2);
    scan_apply_k<<<sc2, 256, 0, stream>>>(cntA, MMn, scanb, offA);
    scan_sums_k<<<sc2, 256, 0, stream>>>(cntB, MMn, scanb);
    scan_tops_k<<<1, 256, 0, stream>>>(scanb, sc2);
    scan_apply_k<<<sc2, 256, 0, stream>>>(cntB, MMn, scanb, offB);

    // ---- emb stats + normalized fp16 table ----
    tabstats_k<<<1, 256, 0, stream>>>(emb, freq, NV, stats);
    tnorm_k<<<cdiv_l((long)NV * DD, 256), 256, 0, stream>>>(emb, stats, egw, egb, egm, Tn, NV);

    // ---- bucketed CSR fills (one staging buffer, serialized on stream) ----
    bcur_init_k<<<cdiv_l(nb1, 256), 256, 0, stream>>>(off1, nb1, bcur);
    stage_k<<<cdiv_l(NE1, 256), 256, 0, stream>>>(edge1 + NE1, edge1, NE1, bcur, stg);
    fill_stage_k<<<cdiv_l(NE1, 256), 256, 0, stream>>>(stg, NE1, off1, cnt1, rows1);
    bcur_init_k<<<cdiv_l(nb2, 256), 256, 0, stream>>>(offA, nb2, bcur);
    stage_k<<<cdiv_l(NE2, 256), 256, 0, stream>>>(edge2 + NE2, edge2, NE2, bcur, stg);
    fill_stage_k<<<cdiv_l(NE2, 256), 256, 0, stream>>>(stg, NE2, offA, cntA, rowsA);
    bcur_init_k<<<cdiv_l(nb2, 256), 256, 0, stream>>>(offB, nb2, bcur);
    stage_k<<<cdiv_l(NE2, 256), 256, 0, stream>>>(edge2, edge2 + NE2, NE2, bcur, stg);
    fill_stage_k<<<cdiv_l(NE2, 256), 256, 0, stream>>>(stg, NE2, offB, cntB, rowsB);

    // ---- conv1 l0: table-gather + mm -> BB, stats slot1 ----
    gcn_tab_fused_k<<<cdiv_l(NN, 4), 256, 0, stream>>>(Tn, x, off1, rows1, dinv1, c1W, c1b, BB, NN);
    gn_stats_k<<<1024, 256, 0, stream>>>((const __half2*)BB, (long)NN * 32, stats + 128);

    // ---- conv1 l1: gather(norm+relu) + mm -> BA, stats slot2 ----
    gcn_fused_k<2><<<cdiv_l(NN, 4), 256, 0, stream>>>(BB, off1, rows1, dinv1,
        stats + 128, c1gw, c1gb, c1gm, (float)NN, c1W + 4096, c1b + 64, BA, NN);
    gn_stats_k<<<1024, 256, 0, stream>>>((const __half2*)BA, (long)NN * 32, stats + 256);

    // ---- pair product (norm+relu fused on reads) -> BC ----
    pair_norm_mul_k<<<cdiv_l(MMn, 4), 256, 0, stream>>>(BA, pos1,
        stats + 256, c1gw + 64, c1gb + 64, c1gm + 64, BC);

    // ---- conv2 l0 ----
    gcn_fused_k<0><<<cdiv_l(MMn, 4), 256, 0, stream>>>(BC, offA, rowsA, dinv2,
        stats, nullptr, nullptr, nullptr, 1.f, c2W, c2b, BB, MMn);
    gn_stats_k<<<1024, 256, 0, stream>>>((const __half2*)BB, (long)MMn * 32, stats + 384);
    gcn_fused_k<0><<<cdiv_l(MMn, 4), 256, 0, stream>>>(BC, offB, rowsB, dinv2r,
        stats, nullptr, nullptr, nullptr, 1.f, c2rW, c2rb, BA, MMn);
    gn_stats_k<<<1024, 256, 0, stream>>>((const __half2*)BA, (long)MMn * 32, stats + 512);
    dualadd_k<<<1024, 256, 0, stream>>>((const __half2*)BB, (const __half2*)BA,
        stats + 384, c2gw, c2gb, c2gm,
        stats + 512, c2rgw, c2rgb, c2rgm, (__half2*)BC);

    // ---- conv2 l1 ----
    gcn_fused_k<0><<<cdiv_l(MMn, 4), 256, 0, stream>>>(BC, offA, rowsA, dinv2,
        stats, nullptr, nullptr, nullptr, 1.f, c2W + 4096, c2b + 64, BB, MMn);
    gn_stats_k<<<1024, 256, 0, stream>>>((const __half2*)BB, (long)MMn * 32, stats + 640);
    gcn_fused_k<0><<<cdiv_l(MMn, 4), 256, 0, stream>>>(BC, offB, rowsB, dinv2r,
        stats, nullptr, nullptr, nullptr, 1.f, c2rW + 4096, c2rb + 64, BA, MMn);
    gn_stats_k<<<1024, 256, 0, stream>>>((const __half2*)BA, (long)MMn * 32, stats + 768);

    // ---- final ----
    final_fused_k<<<cdiv_l(out_size, 4), 256, 0, stream>>>(BB, BA, pos2,
        stats + 640, c2gw + 64, c2gb + 64, c2gm + 64,
        stats + 768, c2rgw + 64, c2rgb + 64, c2rgm + 64,
        predW, predb, out, out_size);
}

// Round 6
// 2352.800 us; speedup vs baseline: 2.8404x; 1.3479x over previous
//
#include <hip/hip_runtime.h>
#include <hip/hip_fp16.h>

#define NN 100000      // nodes graph 1
#define MMn 200000     // nodes graph 2 (link nodes)
#define DD 64
#define NE1 3200000
#define NE2 3200000
#define SHB 6          // 64-node buckets
#define NB1 1563       // ceil(NN/64)
#define NB2 3125       // MMn/64
#define CAP1 2560      // g1 bucket capacity: mean 2048 + ~11 sigma
#define CAP2 1536      // g2 bucket capacity: mean 1024 + ~16 sigma
#define NBLK 128       // staging blocks

static inline int cdiv_l(long a, long b) { return (int)((a + b - 1) / b); }

// ================= small utility kernels =================
__global__ void fill_i32_k(int* p, int v, long n) {
    long i = (long)blockIdx.x * blockDim.x + threadIdx.x;
    long st = (long)gridDim.x * blockDim.x;
    for (; i < n; i += st) p[i] = v;
}
__global__ void fill_f32_k(float* p, float v, long n) {
    long i = (long)blockIdx.x * blockDim.x + threadIdx.x;
    long st = (long)gridDim.x * blockDim.x;
    for (; i < n; i += st) p[i] = v;
}
__global__ void ginit_k(int* gcur, int nb, int cap) {
    int b = blockIdx.x * blockDim.x + threadIdx.x;
    if (b < nb) gcur[b] = b * cap;
}
__global__ void histx_k(const int* __restrict__ x, int n, int* __restrict__ freq) {
    int i = blockIdx.x * blockDim.x + threadIdx.x;
    if (i < n) atomicAdd(&freq[x[i]], 1);
}

// ================= atomic-light bucketed staging =================
// Per block: LDS histogram of its chunk -> one global atomicAdd per (block,bucket)
// segment reservation -> dense placement. ~400K global atomics instead of 3.2M
// (each global atomic costs a 32B HBM write-through on gfx950 - round-5 PMC).
__global__ __launch_bounds__(256) void stage_one_k(
    const int* __restrict__ keys, const int* __restrict__ vals, int ne,
    int* __restrict__ gcur, int2* __restrict__ stg, int nb, int cap)
{
    __shared__ int lcnt[3200];
    __shared__ int lbase[3200];
    int tid = threadIdx.x;
    for (int b = tid; b < nb; b += 256) lcnt[b] = 0;
    __syncthreads();
    int chunk = (ne + (int)gridDim.x - 1) / (int)gridDim.x;
    int s = blockIdx.x * chunk, e = min(ne, s + chunk);
    for (int i = s + tid; i < e; i += 256) atomicAdd(&lcnt[keys[i] >> SHB], 1);
    __syncthreads();
    for (int b = tid; b < nb; b += 256) {
        int c = lcnt[b];
        lbase[b] = c ? atomicAdd(&gcur[b], c) : 0;
        lcnt[b] = 0;
    }
    __syncthreads();
    for (int i = s + tid; i < e; i += 256) {
        int k = keys[i];
        int bkt = k >> SHB;
        int idx = atomicAdd(&lcnt[bkt], 1);   // LDS cursor
        long pos = (long)lbase[bkt] + idx;
        if (pos < (long)(bkt + 1) * cap) stg[pos] = make_int2(vals[i], k);
    }
}

// ================= bucket-local CSR fill: zero global atomics =================
// One block per 64-node bucket: LDS degree count + local scan -> rows, offs(int2), dinv.
template <int CAPT>
__global__ __launch_bounds__(256) void fill_one_k(
    const int2* __restrict__ stg, const int* __restrict__ gcur, int n,
    int* __restrict__ rows, int2* __restrict__ offs, float* __restrict__ dinv)
{
    __shared__ int2 ent[CAPT];
    __shared__ int deg[64];
    __shared__ int sstart[65];
    int b = blockIdx.x, tid = threadIdx.x;
    long s = (long)b * CAPT;
    int cnt = min(gcur[b] - (int)s, CAPT);
    if (tid < 64) deg[tid] = 0;
    __syncthreads();
    for (int i = tid; i < cnt; i += 256) {
        int2 u = stg[s + i];
        ent[i] = u;
        atomicAdd(&deg[u.y & 63], 1);
    }
    __syncthreads();
    if (tid == 0) {
        int acc = 0;
#pragma unroll
        for (int j = 0; j < 64; ++j) { sstart[j] = acc; acc += deg[j]; }
        sstart[64] = acc;
    }
    __syncthreads();
    int node = (b << SHB) + tid;
    if (tid < 64 && node < n) {
        int st = sstart[tid], en = sstart[tid + 1];
        offs[node] = make_int2((int)s + st, (int)s + en);
        dinv[node] = rsqrtf((float)(en - st) + 1.0f);
    }
    if (tid < 64) deg[tid] = sstart[tid];  // reuse as cursor
    __syncthreads();
    for (int i = tid; i < cnt; i += 256) {
        int2 u = ent[i];
        int idx = atomicAdd(&deg[u.y & 63], 1);   // LDS cursor
        rows[s + idx] = u.x;
    }
}

// ================= GraphNorm coefficient (inline, per consumer) =================
__device__ __forceinline__ void gn_coef(const float* __restrict__ stats,
                                        const float* __restrict__ w, const float* __restrict__ b,
                                        const float* __restrict__ ms, float nrows, int d,
                                        float& sc, float& sh) {
    float mean = stats[d] / nrows;
    float ex2 = stats[64 + d] / nrows;
    float m = ms[d];
    float var = ex2 - mean * mean * (2.f * m - m * m);
    float is = rsqrtf(var + 1e-5f);
    sc = is * w[d];
    sh = b[d] - m * mean * sc;
}

// ================= embedding-table stats (frequency-weighted moments) =================
__global__ __launch_bounds__(256) void tabstats_k(const float* __restrict__ T, const int* __restrict__ freq,
                                                  int nv, float* __restrict__ stats) {
    __shared__ float sS[256], sQ[256];
    int tid = threadIdx.x; int d = tid & 63; int g = tid >> 6;
    float s = 0.f, q = 0.f;
    for (int v = g; v < nv; v += 4) {
        float f = (float)freq[v];
        float t = T[(long)v * DD + d];
        s += f * t; q += f * t * t;
    }
    sS[tid] = s; sQ[tid] = q; __syncthreads();
    if (tid < 128) { sS[tid] += sS[tid + 128]; sQ[tid] += sQ[tid + 128]; }
    __syncthreads();
    if (tid < 64) { stats[d] = sS[tid] + sS[tid + 64]; stats[64 + d] = sQ[tid] + sQ[tid + 64]; }
}

// ================= normalized fp16 embedding table =================
__global__ void tnorm_k(const float* __restrict__ T, const float* __restrict__ stats,
                        const float* __restrict__ w, const float* __restrict__ b,
                        const float* __restrict__ ms, __half* __restrict__ Tn, int nv) {
    int i = blockIdx.x * blockDim.x + threadIdx.x;
    if (i >= nv * DD) return;
    int d = i & 63;
    float sc, sh;
    gn_coef(stats, w, b, ms, (float)NN, d, sc, sh);
    Tn[i] = __float2half(fmaf(T[i], sc, sh));
}

// ================= column stats over fp16 matrix (sum, sumsq) =================
__global__ __launch_bounds__(256) void gn_stats_k(const __half2* __restrict__ xx, long nu,
                                                  float* __restrict__ stats) {
    __shared__ float s0[256], s1[256], q0[256], q1[256];
    int tid = threadIdx.x;
    float a0 = 0.f, a1 = 0.f, b0 = 0.f, b1 = 0.f;
    for (long i = (long)blockIdx.x * 256 + tid; i < nu; i += (long)gridDim.x * 256) {
        __half2 u = xx[i];
        float x0 = __low2float(u), x1 = __high2float(u);
        a0 += x0; b0 += x0 * x0;
        a1 += x1; b1 += x1 * x1;
    }
    s0[tid] = a0; s1[tid] = a1; q0[tid] = b0; q1[tid] = b1;
    __syncthreads();
    for (int o = 128; o >= 32; o >>= 1) {
        if (tid < o) { s0[tid] += s0[tid + o]; s1[tid] += s1[tid + o]; q0[tid] += q0[tid + o]; q1[tid] += q1[tid + o]; }
        __syncthreads();
    }
    if (tid < 32) {
        int d0 = 2 * tid;
        atomicAdd(&stats[d0], s0[tid]);
        atomicAdd(&stats[d0 + 1], s1[tid]);
        atomicAdd(&stats[64 + d0], q0[tid]);
        atomicAdd(&stats[64 + d0 + 1], q1[tid]);
    }
}

// ================= fused GCN layer: gather(+opt norm/relu on reads) + matmul + bias =================
// NORM: 0 = raw input, 1 = affine (GN, no relu), 2 = affine + relu
template <int NORM>
__global__ __launch_bounds__(256) void gcn_fused_k(
    const __half* __restrict__ hsrc, const int2* __restrict__ offs,
    const int* __restrict__ rows, const float* __restrict__ dinv,
    const float* __restrict__ stats, const float* __restrict__ gw,
    const float* __restrict__ gb, const float* __restrict__ gms, float nprev,
    const float* __restrict__ W, const float* __restrict__ bias,
    __half* __restrict__ Z, int n)
{
    __shared__ float sW[4096];
    __shared__ float sP[256];
    int tid = threadIdx.x;
    for (int i = tid; i < 4096; i += 256) sW[i] = W[i];
    int wr = tid >> 6, d = tid & 63;
    int node = blockIdx.x * 4 + wr;
    float sc = 1.f, sh = 0.f;
    if (NORM) gn_coef(stats, gw, gb, gms, nprev, d, sc, sh);
    float P = 0.f;
    if (node < n) {
        int2 se = offs[node];
        int s = se.x, e = se.y;
        float dc = dinv[node];
        float x = __half2float(hsrc[(long)node * DD + d]);
        if (NORM) { x = fmaf(x, sc, sh); if (NORM == 2) x = fmaxf(x, 0.f); }
        float a0 = x * dc, a1 = 0.f, a2 = 0.f, a3 = 0.f;
        int i = s;
        for (; i + 3 < e; i += 4) {
            int r0 = rows[i], r1 = rows[i + 1], r2 = rows[i + 2], r3 = rows[i + 3];
            float x0 = __half2float(hsrc[(long)r0 * DD + d]);
            float x1 = __half2float(hsrc[(long)r1 * DD + d]);
            float x2 = __half2float(hsrc[(long)r2 * DD + d]);
            float x3 = __half2float(hsrc[(long)r3 * DD + d]);
            float w0 = dinv[r0], w1 = dinv[r1], w2 = dinv[r2], w3 = dinv[r3];
            if (NORM) {
                x0 = fmaf(x0, sc, sh); x1 = fmaf(x1, sc, sh);
                x2 = fmaf(x2, sc, sh); x3 = fmaf(x3, sc, sh);
                if (NORM == 2) {
                    x0 = fmaxf(x0, 0.f); x1 = fmaxf(x1, 0.f);
                    x2 = fmaxf(x2, 0.f); x3 = fmaxf(x3, 0.f);
                }
            }
            a0 = fmaf(x0, w0, a0); a1 = fmaf(x1, w1, a1);
            a2 = fmaf(x2, w2, a2); a3 = fmaf(x3, w3, a3);
        }
        for (; i < e; ++i) {
            int r = rows[i];
            float xx = __half2float(hsrc[(long)r * DD + d]);
            if (NORM) { xx = fmaf(xx, sc, sh); if (NORM == 2) xx = fmaxf(xx, 0.f); }
            a0 = fmaf(xx, dinv[r], a0);
        }
        P = ((a0 + a1) + (a2 + a3)) * dc;
    }
    sP[wr * 64 + d] = P;
    __syncthreads();
    float z = bias[d];
#pragma unroll
    for (int k = 0; k < 64; ++k) z = fmaf(sP[wr * 64 + k], sW[k * 64 + d], z);
    if (node < n) Z[(long)node * DD + d] = __float2half(z);
}

// ================= conv1-l0: gather directly from normalized fp16 table =================
__global__ __launch_bounds__(256) void gcn_tab_fused_k(
    const __half* __restrict__ Tn, const int* __restrict__ xidx,
    const int2* __restrict__ offs, const int* __restrict__ rows,
    const float* __restrict__ dinv,
    const float* __restrict__ W, const float* __restrict__ bias,
    __half* __restrict__ Z, int n)
{
    __shared__ float sW[4096];
    __shared__ float sP[256];
    int tid = threadIdx.x;
    for (int i = tid; i < 4096; i += 256) sW[i] = W[i];
    int wr = tid >> 6, d = tid & 63;
    int node = blockIdx.x * 4 + wr;
    float P = 0.f;
    if (node < n) {
        int2 se = offs[node];
        int s = se.x, e = se.y;
        float dc = dinv[node];
        float a0 = __half2float(Tn[(long)xidx[node] * DD + d]) * dc;
        float a1 = 0.f, a2 = 0.f, a3 = 0.f;
        int i = s;
        for (; i + 3 < e; i += 4) {
            int r0 = rows[i], r1 = rows[i + 1], r2 = rows[i + 2], r3 = rows[i + 3];
            int x0 = xidx[r0], x1 = xidx[r1], x2 = xidx[r2], x3 = xidx[r3];
            float w0 = dinv[r0], w1 = dinv[r1], w2 = dinv[r2], w3 = dinv[r3];
            a0 = fmaf(__half2float(Tn[(long)x0 * DD + d]), w0, a0);
            a1 = fmaf(__half2float(Tn[(long)x1 * DD + d]), w1, a1);
            a2 = fmaf(__half2float(Tn[(long)x2 * DD + d]), w2, a2);
            a3 = fmaf(__half2float(Tn[(long)x3 * DD + d]), w3, a3);
        }
        for (; i < e; ++i) {
            int r = rows[i];
            a0 = fmaf(__half2float(Tn[(long)xidx[r] * DD + d]), dinv[r], a0);
        }
        P = ((a0 + a1) + (a2 + a3)) * dc;
    }
    sP[wr * 64 + d] = P;
    __syncthreads();
    float z = bias[d];
#pragma unroll
    for (int k = 0; k < 64; ++k) z = fmaf(sP[wr * 64 + k], sW[k * 64 + d], z);
    if (node < n) Z[(long)node * DD + d] = __float2half(z);
}

// ================= link-pair product with fused GN+relu on reads =================
__global__ __launch_bounds__(256) void pair_norm_mul_k(
    const __half* __restrict__ Z2, const int* __restrict__ pos,
    const float* __restrict__ stats, const float* __restrict__ gw,
    const float* __restrict__ gb, const float* __restrict__ gms,
    __half* __restrict__ h2)
{
    int tid = threadIdx.x, wr = tid >> 6, d = tid & 63;
    int idx = blockIdx.x * 4 + wr;
    if (idx >= MMn) return;
    float sc, sh;
    gn_coef(stats, gw, gb, gms, (float)NN, d, sc, sh);
    int p0 = pos[2 * idx], p1 = pos[2 * idx + 1];
    float v0 = fmaxf(fmaf(__half2float(Z2[(long)p0 * DD + d]), sc, sh), 0.f);
    float v1 = fmaxf(fmaf(__half2float(Z2[(long)p1 * DD + d]), sc, sh), 0.f);
    h2[(long)idx * DD + d] = __float2half(v0 * v1);
}

// ================= dual-branch GN+relu+add =================
__global__ __launch_bounds__(256) void dualadd_k(
    const __half2* __restrict__ Za, const __half2* __restrict__ Zb,
    const float* __restrict__ stA, const float* __restrict__ wA, const float* __restrict__ bA, const float* __restrict__ msA,
    const float* __restrict__ stB, const float* __restrict__ wB, const float* __restrict__ bB, const float* __restrict__ msB,
    __half2* __restrict__ hout)
{
    const long nu = (long)MMn * 32;
    int tid = threadIdx.x;
    int d0 = (2 * tid) & 63;
    float scA0, shA0, scA1, shA1, scB0, shB0, scB1, shB1;
    gn_coef(stA, wA, bA, msA, (float)MMn, d0, scA0, shA0);
    gn_coef(stA, wA, bA, msA, (float)MMn, d0 + 1, scA1, shA1);
    gn_coef(stB, wB, bB, msB, (float)MMn, d0, scB0, shB0);
    gn_coef(stB, wB, bB, msB, (float)MMn, d0 + 1, scB1, shB1);
    for (long i = (long)blockIdx.x * 256 + tid; i < nu; i += (long)gridDim.x * 256) {
        __half2 ua = Za[i], ub = Zb[i];
        float a0 = __low2float(ua), a1 = __high2float(ua);
        float c0 = __low2float(ub), c1 = __high2float(ub);
        float o0 = fmaxf(fmaf(a0, scA0, shA0), 0.f) + fmaxf(fmaf(c0, scB0, shB0), 0.f);
        float o1 = fmaxf(fmaf(a1, scA1, shA1), 0.f) + fmaxf(fmaf(c1, scB1, shB1), 0.f);
        hout[i] = __halves2half2(__float2half(o0), __float2half(o1));
    }
}

// ================= final: dual GN+relu+add on reads, pair product, dot predW =================
__global__ __launch_bounds__(256) void final_fused_k(
    const __half* __restrict__ Za, const __half* __restrict__ Zb,
    const int* __restrict__ pos2,
    const float* __restrict__ stA, const float* __restrict__ wA, const float* __restrict__ bA, const float* __restrict__ msA,
    const float* __restrict__ stB, const float* __restrict__ wB, const float* __restrict__ bB, const float* __restrict__ msB,
    const float* __restrict__ pw, const float* __restrict__ pb,
    float* __restrict__ out, int nout)
{
    int tid = threadIdx.x, wr = tid >> 6, d = tid & 63;
    int i = blockIdx.x * 4 + wr;
    if (i >= nout) return;
    float scA, shA, scB, shB;
    gn_coef(stA, wA, bA, msA, (float)MMn, d, scA, shA);
    gn_coef(stB, wB, bB, msB, (float)MMn, d, scB, shB);
    int p0 = pos2[2 * i], p1 = pos2[2 * i + 1];
    float v0 = fmaxf(fmaf(__half2float(Za[(long)p0 * DD + d]), scA, shA), 0.f)
             + fmaxf(fmaf(__half2float(Zb[(long)p0 * DD + d]), scB, shB), 0.f);
    float v1 = fmaxf(fmaf(__half2float(Za[(long)p1 * DD + d]), scA, shA), 0.f)
             + fmaxf(fmaf(__half2float(Zb[(long)p1 * DD + d]), scB, shB), 0.f);
    float v = v0 * v1 * pw[d];
#pragma unroll
    for (int o = 32; o > 0; o >>= 1) v += __shfl_down(v, o, 64);
    if (d == 0) out[i] = v + pb[0];
}

extern "C" void kernel_launch(void* const* d_in, const int* in_sizes, int n_in,
                              void* d_out, int out_size, void* d_ws, size_t ws_size,
                              hipStream_t stream) {
    const int* x      = (const int*)d_in[0];
    const int* edge1  = (const int*)d_in[2];
    const int* edge2  = (const int*)d_in[3];
    const int* pos1   = (const int*)d_in[5];
    const int* pos2   = (const int*)d_in[6];
    const float* emb  = (const float*)d_in[7];
    const float* egw  = (const float*)d_in[8];
    const float* egb  = (const float*)d_in[9];
    const float* egm  = (const float*)d_in[10];
    const float* c1W  = (const float*)d_in[11];
    const float* c1b  = (const float*)d_in[12];
    const float* c1gw = (const float*)d_in[13];
    const float* c1gb = (const float*)d_in[14];
    const float* c1gm = (const float*)d_in[15];
    const float* c2W  = (const float*)d_in[16];
    const float* c2b  = (const float*)d_in[17];
    const float* c2gw = (const float*)d_in[18];
    const float* c2gb = (const float*)d_in[19];
    const float* c2gm = (const float*)d_in[20];
    const float* c2rW  = (const float*)d_in[21];
    const float* c2rb  = (const float*)d_in[22];
    const float* c2rgw = (const float*)d_in[23];
    const float* c2rgb = (const float*)d_in[24];
    const float* c2rgm = (const float*)d_in[25];
    const float* predW = (const float*)d_in[26];
    const float* predb = (const float*)d_in[27];
    float* out = (float*)d_out;
    const int NV = 1001;   // emb table rows (MAXX+1)

    // ---- workspace layout (~176 MB) ----
    char* p = (char*)d_ws;
    const long SZH = (long)MMn * DD;  // elements per fp16 node buffer
    __half* BA = (__half*)p; p += SZH * 2;
    __half* BB = (__half*)p; p += SZH * 2;
    __half* BC = (__half*)p; p += SZH * 2;
    int2* stg  = (int2*)p;  p += (long)NB2 * CAP2 * 8;      // 38.4 MB (>= NB1*CAP1*8 = 32 MB)
    int* rows1 = (int*)p; p += (long)NB1 * CAP1 * 4;        // 16 MB
    int* rowsA = (int*)p; p += (long)NB2 * CAP2 * 4;        // 19.2 MB
    int* rowsB = (int*)p; p += (long)NB2 * CAP2 * 4;        // 19.2 MB
    int2* offs1 = (int2*)p; p += (long)NN * 8;
    int2* offsA = (int2*)p; p += (long)MMn * 8;
    int2* offsB = (int2*)p; p += (long)MMn * 8;
    float* dinv1  = (float*)p; p += (long)NN * 4;
    float* dinv2  = (float*)p; p += (long)MMn * 4;
    float* dinv2r = (float*)p; p += (long)MMn * 4;
    int* gcur1 = (int*)p; p += 2048 * 4;
    int* gcurA = (int*)p; p += 4096 * 4;
    int* gcurB = (int*)p; p += 4096 * 4;
    int* freq = (int*)p; p += 1024 * 4;
    float* stats = (float*)p; p += 7 * 128 * 4;   // slots 0..6
    __half* Tn = (__half*)p; p += (long)NV * DD * 2;
    if ((size_t)(p - (char*)d_ws) > ws_size) return;

    // ---- zero freq + stats ----
    fill_i32_k<<<4, 256, 0, stream>>>(freq, 0, 1024);
    fill_f32_k<<<1, 256, 0, stream>>>(stats, 0.f, 7 * 128);

    // ---- emb-frequency histogram + table norm ----
    histx_k<<<cdiv_l(NN, 256), 256, 0, stream>>>(x, NN, freq);
    tabstats_k<<<1, 256, 0, stream>>>(emb, freq, NV, stats);
    tnorm_k<<<cdiv_l((long)NV * DD, 256), 256, 0, stream>>>(emb, stats, egw, egb, egm, Tn, NV);

    // ---- CSR build, atomic-light (g1, then g2 fwd, then g2 rev; stg reused serially) ----
    ginit_k<<<cdiv_l(NB1, 256), 256, 0, stream>>>(gcur1, NB1, CAP1);
    stage_one_k<<<NBLK, 256, 0, stream>>>(edge1 + NE1, edge1, NE1, gcur1, stg, NB1, CAP1);
    fill_one_k<CAP1><<<NB1, 256, 0, stream>>>(stg, gcur1, NN, rows1, offs1, dinv1);

    ginit_k<<<cdiv_l(NB2, 256), 256, 0, stream>>>(gcurA, NB2, CAP2);
    stage_one_k<<<NBLK, 256, 0, stream>>>(edge2 + NE2, edge2, NE2, gcurA, stg, NB2, CAP2);
    fill_one_k<CAP2><<<NB2, 256, 0, stream>>>(stg, gcurA, MMn, rowsA, offsA, dinv2);

    ginit_k<<<cdiv_l(NB2, 256), 256, 0, stream>>>(gcurB, NB2, CAP2);
    stage_one_k<<<NBLK, 256, 0, stream>>>(edge2, edge2 + NE2, NE2, gcurB, stg, NB2, CAP2);
    fill_one_k<CAP2><<<NB2, 256, 0, stream>>>(stg, gcurB, MMn, rowsB, offsB, dinv2r);

    // ---- conv1 l0: table-gather + mm -> BB, stats slot1 ----
    gcn_tab_fused_k<<<cdiv_l(NN, 4), 256, 0, stream>>>(Tn, x, offs1, rows1, dinv1, c1W, c1b, BB, NN);
    gn_stats_k<<<1024, 256, 0, stream>>>((const __half2*)BB, (long)NN * 32, stats + 128);

    // ---- conv1 l1: gather(norm+relu) + mm -> BA, stats slot2 ----
    gcn_fused_k<2><<<cdiv_l(NN, 4), 256, 0, stream>>>(BB, offs1, rows1, dinv1,
        stats + 128, c1gw, c1gb, c1gm, (float)NN, c1W + 4096, c1b + 64, BA, NN);
    gn_stats_k<<<1024, 256, 0, stream>>>((const __half2*)BA, (long)NN * 32, stats + 256);

    // ---- pair product (norm+relu fused on reads) -> BC ----
    pair_norm_mul_k<<<cdiv_l(MMn, 4), 256, 0, stream>>>(BA, pos1,
        stats + 256, c1gw + 64, c1gb + 64, c1gm + 64, BC);

    // ---- conv2 l0 ----
    gcn_fused_k<0><<<cdiv_l(MMn, 4), 256, 0, stream>>>(BC, offsA, rowsA, dinv2,
        stats, nullptr, nullptr, nullptr, 1.f, c2W, c2b, BB, MMn);
    gn_stats_k<<<1024, 256, 0, stream>>>((const __half2*)BB, (long)MMn * 32, stats + 384);
    gcn_fused_k<0><<<cdiv_l(MMn, 4), 256, 0, stream>>>(BC, offsB, rowsB, dinv2r,
        stats, nullptr, nullptr, nullptr, 1.f, c2rW, c2rb, BA, MMn);
    gn_stats_k<<<1024, 256, 0, stream>>>((const __half2*)BA, (long)MMn * 32, stats + 512);
    dualadd_k<<<1024, 256, 0, stream>>>((const __half2*)BB, (const __half2*)BA,
        stats + 384, c2gw, c2gb, c2gm,
        stats + 512, c2rgw, c2rgb, c2rgm, (__half2*)BC);

    // ---- conv2 l1 ----
    gcn_fused_k<0><<<cdiv_l(MMn, 4), 256, 0, stream>>>(BC, offsA, rowsA, dinv2,
        stats, nullptr, nullptr, nullptr, 1.f, c2W + 4096, c2b + 64, BB, MMn);
    gn_stats_k<<<1024, 256, 0, stream>>>((const __half2*)BB, (long)MMn * 32, stats + 640);
    gcn_fused_k<0><<<cdiv_l(MMn, 4), 256, 0, stream>>>(BC, offsB, rowsB, dinv2r,
        stats, nullptr, nullptr, nullptr, 1.f, c2rW + 4096, c2rb + 64, BA, MMn);
    gn_stats_k<<<1024, 256, 0, stream>>>((const __half2*)BA, (long)MMn * 32, stats + 768);

    // ---- final ----
    final_fused_k<<<cdiv_l(out_size, 4), 256, 0, stream>>>(BB, BA, pos2,
        stats + 640, c2gw + 64, c2gb + 64, c2gm + 64,
        stats + 768, c2rgw + 64, c2rgb + 64, c2rgm + 64,
        predW, predb, out, out_size);
}

// Round 7
// 1736.475 us; speedup vs baseline: 3.8485x; 1.3549x over previous
//
#include <hip/hip_runtime.h>
#include <hip/hip_fp16.h>

#define NN 100000      // nodes graph 1
#define MMn 200000     // nodes graph 2 (link nodes)
#define DD 64
#define NE1 3200000
#define NE2 3200000
#define SHB 6          // 64-node buckets
#define NB1 1563       // ceil(NN/64)
#define NB2 3125       // MMn/64
#define CAP1 2560      // g1 bucket capacity: mean 2048 + ~11 sigma
#define CAP2 1536      // g2 bucket capacity: mean 1024 + ~16 sigma
#define NBLK 128       // staging blocks
#define GGRID 2048     // grid-stride blocks for gcn kernels

static inline int cdiv_l(long a, long b) { return (int)((a + b - 1) / b); }

// ================= small utility kernels =================
__global__ void fill_i32_k(int* p, int v, long n) {
    long i = (long)blockIdx.x * blockDim.x + threadIdx.x;
    long st = (long)gridDim.x * blockDim.x;
    for (; i < n; i += st) p[i] = v;
}
__global__ void fill_f32_k(float* p, float v, long n) {
    long i = (long)blockIdx.x * blockDim.x + threadIdx.x;
    long st = (long)gridDim.x * blockDim.x;
    for (; i < n; i += st) p[i] = v;
}
__global__ void ginit_k(int* gcur, int nb, int cap) {
    int b = blockIdx.x * blockDim.x + threadIdx.x;
    if (b < nb) gcur[b] = b * cap;
}
__global__ void histx_k(const int* __restrict__ x, int n, int* __restrict__ freq) {
    int i = blockIdx.x * blockDim.x + threadIdx.x;
    if (i < n) atomicAdd(&freq[x[i]], 1);
}

// ================= atomic-light bucketed staging (round-6, proven) =================
__global__ __launch_bounds__(256) void stage_one_k(
    const int* __restrict__ keys, const int* __restrict__ vals, int ne,
    int* __restrict__ gcur, int2* __restrict__ stg, int nb, int cap)
{
    __shared__ int lcnt[3200];
    __shared__ int lbase[3200];
    int tid = threadIdx.x;
    for (int b = tid; b < nb; b += 256) lcnt[b] = 0;
    __syncthreads();
    int chunk = (ne + (int)gridDim.x - 1) / (int)gridDim.x;
    int s = blockIdx.x * chunk, e = min(ne, s + chunk);
    for (int i = s + tid; i < e; i += 256) atomicAdd(&lcnt[keys[i] >> SHB], 1);
    __syncthreads();
    for (int b = tid; b < nb; b += 256) {
        int c = lcnt[b];
        lbase[b] = c ? atomicAdd(&gcur[b], c) : 0;
        lcnt[b] = 0;
    }
    __syncthreads();
    for (int i = s + tid; i < e; i += 256) {
        int k = keys[i];
        int bkt = k >> SHB;
        int idx = atomicAdd(&lcnt[bkt], 1);   // LDS cursor
        long pos = (long)lbase[bkt] + idx;
        if (pos < (long)(bkt + 1) * cap) stg[pos] = make_int2(vals[i], k);
    }
}

// ================= bucket-local CSR fill: zero global atomics =================
template <int CAPT>
__global__ __launch_bounds__(256) void fill_one_k(
    const int2* __restrict__ stg, const int* __restrict__ gcur, int n,
    int* __restrict__ rows, int2* __restrict__ offs, float* __restrict__ dinv)
{
    __shared__ int2 ent[CAPT];
    __shared__ int deg[64];
    __shared__ int sstart[65];
    int b = blockIdx.x, tid = threadIdx.x;
    long s = (long)b * CAPT;
    int cnt = min(gcur[b] - (int)s, CAPT);
    if (tid < 64) deg[tid] = 0;
    __syncthreads();
    for (int i = tid; i < cnt; i += 256) {
        int2 u = stg[s + i];
        ent[i] = u;
        atomicAdd(&deg[u.y & 63], 1);
    }
    __syncthreads();
    if (tid == 0) {
        int acc = 0;
#pragma unroll
        for (int j = 0; j < 64; ++j) { sstart[j] = acc; acc += deg[j]; }
        sstart[64] = acc;
    }
    __syncthreads();
    int node = (b << SHB) + tid;
    if (tid < 64 && node < n) {
        int st = sstart[tid], en = sstart[tid + 1];
        offs[node] = make_int2((int)s + st, (int)s + en);
        dinv[node] = rsqrtf((float)(en - st) + 1.0f);
    }
    if (tid < 64) deg[tid] = sstart[tid];  // reuse as cursor
    __syncthreads();
    for (int i = tid; i < cnt; i += 256) {
        int2 u = ent[i];
        int idx = atomicAdd(&deg[u.y & 63], 1);   // LDS cursor
        rows[s + idx] = u.x;
    }
}

// ================= GraphNorm coefficient (inline, per consumer) =================
__device__ __forceinline__ void gn_coef(const float* __restrict__ stats,
                                        const float* __restrict__ w, const float* __restrict__ b,
                                        const float* __restrict__ ms, float nrows, int d,
                                        float& sc, float& sh) {
    float mean = stats[d] / nrows;
    float ex2 = stats[64 + d] / nrows;
    float m = ms[d];
    float var = ex2 - mean * mean * (2.f * m - m * m);
    float is = rsqrtf(var + 1e-5f);
    sc = is * w[d];
    sh = b[d] - m * mean * sc;
}

// ================= embedding-table stats (frequency-weighted moments) =================
__global__ __launch_bounds__(256) void tabstats_k(const float* __restrict__ T, const int* __restrict__ freq,
                                                  int nv, float* __restrict__ stats) {
    __shared__ float sS[256], sQ[256];
    int tid = threadIdx.x; int d = tid & 63; int g = tid >> 6;
    float s = 0.f, q = 0.f;
    for (int v = g; v < nv; v += 4) {
        float f = (float)freq[v];
        float t = T[(long)v * DD + d];
        s += f * t; q += f * t * t;
    }
    sS[tid] = s; sQ[tid] = q; __syncthreads();
    if (tid < 128) { sS[tid] += sS[tid + 128]; sQ[tid] += sQ[tid + 128]; }
    __syncthreads();
    if (tid < 64) { stats[d] = sS[tid] + sS[tid + 64]; stats[64 + d] = sQ[tid] + sQ[tid + 64]; }
}

// ================= normalized fp16 embedding table =================
__global__ void tnorm_k(const float* __restrict__ T, const float* __restrict__ stats,
                        const float* __restrict__ w, const float* __restrict__ b,
                        const float* __restrict__ ms, __half* __restrict__ Tn, int nv) {
    int i = blockIdx.x * blockDim.x + threadIdx.x;
    if (i >= nv * DD) return;
    int d = i & 63;
    float sc, sh;
    gn_coef(stats, w, b, ms, (float)NN, d, sc, sh);
    Tn[i] = __float2half(fmaf(T[i], sc, sh));
}

// ================= fused GCN layer: half2 gather + matmul + bias + fused stats =================
// Lane l: dims (2q,2q+1), q=l&31; lane-groups 0/1 take even/odd edges, combined by shfl_xor(32).
// Grid-stride blocks amortize the 16KB W->LDS load and enable per-block stats reduction.
// NORM: 0 = raw input, 1 = affine (GN, no relu), 2 = affine + relu
template <int NORM>
__global__ __launch_bounds__(256) void gcn_fused_k(
    const __half* __restrict__ hsrc, const int2* __restrict__ offs,
    const int* __restrict__ rows, const float* __restrict__ dinv,
    const float* __restrict__ stats, const float* __restrict__ gw,
    const float* __restrict__ gb, const float* __restrict__ gms, float nprev,
    const float* __restrict__ W, const float* __restrict__ bias,
    __half* __restrict__ Z, float* __restrict__ ostats, int n)
{
    __shared__ float sW[4096];
    __shared__ float sP[256];
    __shared__ float rs[256];
    int tid = threadIdx.x;
    for (int i = tid; i < 4096; i += 256) sW[i] = W[i];
    int wr = tid >> 6, d = tid & 63;
    int q = tid & 31, grp = (tid >> 5) & 1;
    int d0 = q * 2;
    float sc0 = 1.f, sh0 = 0.f, sc1 = 1.f, sh1 = 0.f;
    if (NORM) {
        gn_coef(stats, gw, gb, gms, nprev, d0, sc0, sh0);
        gn_coef(stats, gw, gb, gms, nprev, d0 + 1, sc1, sh1);
    }
    float bd = bias[d];
    float sumz = 0.f, sumq = 0.f;
    const __half2* h2 = (const __half2*)hsrc;
    int ngrp = (n + 3) >> 2;
    for (int g = blockIdx.x; g < ngrp; g += gridDim.x) {
        int node = g * 4 + wr;
        float P0 = 0.f, P1 = 0.f;
        if (node < n) {
            int2 se = offs[node];
            int s = se.x, e = se.y;
            float dc = dinv[node];
            float a0 = 0.f, a1 = 0.f, b0 = 0.f, b1 = 0.f;
            if (!grp) {
                __half2 u = h2[(long)node * 32 + q];
                float x0 = __low2float(u), x1 = __high2float(u);
                if (NORM) {
                    x0 = fmaf(x0, sc0, sh0); x1 = fmaf(x1, sc1, sh1);
                    if (NORM == 2) { x0 = fmaxf(x0, 0.f); x1 = fmaxf(x1, 0.f); }
                }
                a0 = x0 * dc; a1 = x1 * dc;
            }
            int i = s + grp;
            for (; i + 2 < e; i += 4) {
                int r0 = rows[i], r1 = rows[i + 2];
                float w0 = dinv[r0], w1 = dinv[r1];
                __half2 u0 = h2[(long)r0 * 32 + q];
                __half2 u1 = h2[(long)r1 * 32 + q];
                float x00 = __low2float(u0), x01 = __high2float(u0);
                float x10 = __low2float(u1), x11 = __high2float(u1);
                if (NORM) {
                    x00 = fmaf(x00, sc0, sh0); x01 = fmaf(x01, sc1, sh1);
                    x10 = fmaf(x10, sc0, sh0); x11 = fmaf(x11, sc1, sh1);
                    if (NORM == 2) {
                        x00 = fmaxf(x00, 0.f); x01 = fmaxf(x01, 0.f);
                        x10 = fmaxf(x10, 0.f); x11 = fmaxf(x11, 0.f);
                    }
                }
                a0 = fmaf(x00, w0, a0); a1 = fmaf(x01, w0, a1);
                b0 = fmaf(x10, w1, b0); b1 = fmaf(x11, w1, b1);
            }
            if (i < e) {
                int r = rows[i];
                float w0 = dinv[r];
                __half2 u = h2[(long)r * 32 + q];
                float x0 = __low2float(u), x1 = __high2float(u);
                if (NORM) {
                    x0 = fmaf(x0, sc0, sh0); x1 = fmaf(x1, sc1, sh1);
                    if (NORM == 2) { x0 = fmaxf(x0, 0.f); x1 = fmaxf(x1, 0.f); }
                }
                a0 = fmaf(x0, w0, a0); a1 = fmaf(x1, w0, a1);
            }
            a0 += b0; a1 += b1;
            a0 += __shfl_xor(a0, 32, 64);
            a1 += __shfl_xor(a1, 32, 64);
            P0 = a0 * dc; P1 = a1 * dc;
        }
        __syncthreads();   // previous iteration's matmul reads done (also orders sW fill)
        if (!grp) { sP[wr * 64 + d0] = P0; sP[wr * 64 + d0 + 1] = P1; }
        __syncthreads();
        if (node < n) {
            float z = bd;
#pragma unroll
            for (int k = 0; k < 64; ++k) z = fmaf(sP[wr * 64 + k], sW[k * 64 + d], z);
            Z[(long)node * DD + d] = __float2half(z);
            sumz += z; sumq += z * z;
        }
    }
    // block stats reduction: 128 atomics/block
    rs[tid] = sumz; __syncthreads();
    if (tid < 64) atomicAdd(&ostats[tid], rs[tid] + rs[tid + 64] + rs[tid + 128] + rs[tid + 192]);
    __syncthreads();
    rs[tid] = sumq; __syncthreads();
    if (tid < 64) atomicAdd(&ostats[64 + tid], rs[tid] + rs[tid + 64] + rs[tid + 128] + rs[tid + 192]);
}

// ================= conv1-l0: half2 gather from normalized fp16 table (L2-resident) =================
__global__ __launch_bounds__(256) void gcn_tab_fused_k(
    const __half* __restrict__ Tn, const int* __restrict__ xidx,
    const int2* __restrict__ offs, const int* __restrict__ rows,
    const float* __restrict__ dinv,
    const float* __restrict__ W, const float* __restrict__ bias,
    __half* __restrict__ Z, float* __restrict__ ostats, int n)
{
    __shared__ float sW[4096];
    __shared__ float sP[256];
    __shared__ float rs[256];
    int tid = threadIdx.x;
    for (int i = tid; i < 4096; i += 256) sW[i] = W[i];
    int wr = tid >> 6, d = tid & 63;
    int q = tid & 31, grp = (tid >> 5) & 1;
    int d0 = q * 2;
    float bd = bias[d];
    float sumz = 0.f, sumq = 0.f;
    const __half2* t2 = (const __half2*)Tn;
    int ngrp = (n + 3) >> 2;
    for (int g = blockIdx.x; g < ngrp; g += gridDim.x) {
        int node = g * 4 + wr;
        float P0 = 0.f, P1 = 0.f;
        if (node < n) {
            int2 se = offs[node];
            int s = se.x, e = se.y;
            float dc = dinv[node];
            float a0 = 0.f, a1 = 0.f, b0 = 0.f, b1 = 0.f;
            if (!grp) {
                __half2 u = t2[(long)xidx[node] * 32 + q];
                a0 = __low2float(u) * dc; a1 = __high2float(u) * dc;
            }
            int i = s + grp;
            for (; i + 2 < e; i += 4) {
                int r0 = rows[i], r1 = rows[i + 2];
                float w0 = dinv[r0], w1 = dinv[r1];
                __half2 u0 = t2[(long)xidx[r0] * 32 + q];
                __half2 u1 = t2[(long)xidx[r1] * 32 + q];
                a0 = fmaf(__low2float(u0), w0, a0); a1 = fmaf(__high2float(u0), w0, a1);
                b0 = fmaf(__low2float(u1), w1, b0); b1 = fmaf(__high2float(u1), w1, b1);
            }
            if (i < e) {
                int r = rows[i];
                float w0 = dinv[r];
                __half2 u = t2[(long)xidx[r] * 32 + q];
                a0 = fmaf(__low2float(u), w0, a0); a1 = fmaf(__high2float(u), w0, a1);
            }
            a0 += b0; a1 += b1;
            a0 += __shfl_xor(a0, 32, 64);
            a1 += __shfl_xor(a1, 32, 64);
            P0 = a0 * dc; P1 = a1 * dc;
        }
        __syncthreads();
        if (!grp) { sP[wr * 64 + d0] = P0; sP[wr * 64 + d0 + 1] = P1; }
        __syncthreads();
        if (node < n) {
            float z = bd;
#pragma unroll
            for (int k = 0; k < 64; ++k) z = fmaf(sP[wr * 64 + k], sW[k * 64 + d], z);
            Z[(long)node * DD + d] = __float2half(z);
            sumz += z; sumq += z * z;
        }
    }
    rs[tid] = sumz; __syncthreads();
    if (tid < 64) atomicAdd(&ostats[tid], rs[tid] + rs[tid + 64] + rs[tid + 128] + rs[tid + 192]);
    __syncthreads();
    rs[tid] = sumq; __syncthreads();
    if (tid < 64) atomicAdd(&ostats[64 + tid], rs[tid] + rs[tid + 64] + rs[tid + 128] + rs[tid + 192]);
}

// ================= link-pair product with fused GN+relu on reads =================
__global__ __launch_bounds__(256) void pair_norm_mul_k(
    const __half* __restrict__ Z2, const int* __restrict__ pos,
    const float* __restrict__ stats, const float* __restrict__ gw,
    const float* __restrict__ gb, const float* __restrict__ gms,
    __half* __restrict__ h2)
{
    int tid = threadIdx.x, wr = tid >> 6, d = tid & 63;
    int idx = blockIdx.x * 4 + wr;
    if (idx >= MMn) return;
    float sc, sh;
    gn_coef(stats, gw, gb, gms, (float)NN, d, sc, sh);
    int p0 = pos[2 * idx], p1 = pos[2 * idx + 1];
    float v0 = fmaxf(fmaf(__half2float(Z2[(long)p0 * DD + d]), sc, sh), 0.f);
    float v1 = fmaxf(fmaf(__half2float(Z2[(long)p1 * DD + d]), sc, sh), 0.f);
    h2[(long)idx * DD + d] = __float2half(v0 * v1);
}

// ================= dual-branch GN+relu+add =================
__global__ __launch_bounds__(256) void dualadd_k(
    const __half2* __restrict__ Za, const __half2* __restrict__ Zb,
    const float* __restrict__ stA, const float* __restrict__ wA, const float* __restrict__ bA, const float* __restrict__ msA,
    const float* __restrict__ stB, const float* __restrict__ wB, const float* __restrict__ bB, const float* __restrict__ msB,
    __half2* __restrict__ hout)
{
    const long nu = (long)MMn * 32;
    int tid = threadIdx.x;
    int d0 = (2 * tid) & 63;
    float scA0, shA0, scA1, shA1, scB0, shB0, scB1, shB1;
    gn_coef(stA, wA, bA, msA, (float)MMn, d0, scA0, shA0);
    gn_coef(stA, wA, bA, msA, (float)MMn, d0 + 1, scA1, shA1);
    gn_coef(stB, wB, bB, msB, (float)MMn, d0, scB0, shB0);
    gn_coef(stB, wB, bB, msB, (float)MMn, d0 + 1, scB1, shB1);
    for (long i = (long)blockIdx.x * 256 + tid; i < nu; i += (long)gridDim.x * 256) {
        __half2 ua = Za[i], ub = Zb[i];
        float a0 = __low2float(ua), a1 = __high2float(ua);
        float c0 = __low2float(ub), c1 = __high2float(ub);
        float o0 = fmaxf(fmaf(a0, scA0, shA0), 0.f) + fmaxf(fmaf(c0, scB0, shB0), 0.f);
        float o1 = fmaxf(fmaf(a1, scA1, shA1), 0.f) + fmaxf(fmaf(c1, scB1, shB1), 0.f);
        hout[i] = __halves2half2(__float2half(o0), __float2half(o1));
    }
}

// ================= final: dual GN+relu+add on reads, pair product, dot predW =================
__global__ __launch_bounds__(256) void final_fused_k(
    const __half* __restrict__ Za, const __half* __restrict__ Zb,
    const int* __restrict__ pos2,
    const float* __restrict__ stA, const float* __restrict__ wA, const float* __restrict__ bA, const float* __restrict__ msA,
    const float* __restrict__ stB, const float* __restrict__ wB, const float* __restrict__ bB, const float* __restrict__ msB,
    const float* __restrict__ pw, const float* __restrict__ pb,
    float* __restrict__ out, int nout)
{
    int tid = threadIdx.x, wr = tid >> 6, d = tid & 63;
    int i = blockIdx.x * 4 + wr;
    if (i >= nout) return;
    float scA, shA, scB, shB;
    gn_coef(stA, wA, bA, msA, (float)MMn, d, scA, shA);
    gn_coef(stB, wB, bB, msB, (float)MMn, d, scB, shB);
    int p0 = pos2[2 * i], p1 = pos2[2 * i + 1];
    float v0 = fmaxf(fmaf(__half2float(Za[(long)p0 * DD + d]), scA, shA), 0.f)
             + fmaxf(fmaf(__half2float(Zb[(long)p0 * DD + d]), scB, shB), 0.f);
    float v1 = fmaxf(fmaf(__half2float(Za[(long)p1 * DD + d]), scA, shA), 0.f)
             + fmaxf(fmaf(__half2float(Zb[(long)p1 * DD + d]), scB, shB), 0.f);
    float v = v0 * v1 * pw[d];
#pragma unroll
    for (int o = 32; o > 0; o >>= 1) v += __shfl_down(v, o, 64);
    if (d == 0) out[i] = v + pb[0];
}

extern "C" void kernel_launch(void* const* d_in, const int* in_sizes, int n_in,
                              void* d_out, int out_size, void* d_ws, size_t ws_size,
                              hipStream_t stream) {
    const int* x      = (const int*)d_in[0];
    const int* edge1  = (const int*)d_in[2];
    const int* edge2  = (const int*)d_in[3];
    const int* pos1   = (const int*)d_in[5];
    const int* pos2   = (const int*)d_in[6];
    const float* emb  = (const float*)d_in[7];
    const float* egw  = (const float*)d_in[8];
    const float* egb  = (const float*)d_in[9];
    const float* egm  = (const float*)d_in[10];
    const float* c1W  = (const float*)d_in[11];
    const float* c1b  = (const float*)d_in[12];
    const float* c1gw = (const float*)d_in[13];
    const float* c1gb = (const float*)d_in[14];
    const float* c1gm = (const float*)d_in[15];
    const float* c2W  = (const float*)d_in[16];
    const float* c2b  = (const float*)d_in[17];
    const float* c2gw = (const float*)d_in[18];
    const float* c2gb = (const float*)d_in[19];
    const float* c2gm = (const float*)d_in[20];
    const float* c2rW  = (const float*)d_in[21];
    const float* c2rb  = (const float*)d_in[22];
    const float* c2rgw = (const float*)d_in[23];
    const float* c2rgb = (const float*)d_in[24];
    const float* c2rgm = (const float*)d_in[25];
    const float* predW = (const float*)d_in[26];
    const float* predb = (const float*)d_in[27];
    float* out = (float*)d_out;
    const int NV = 1001;   // emb table rows (MAXX+1)

    // ---- workspace layout (~176 MB) ----
    char* p = (char*)d_ws;
    const long SZH = (long)MMn * DD;  // elements per fp16 node buffer
    __half* BA = (__half*)p; p += SZH * 2;
    __half* BB = (__half*)p; p += SZH * 2;
    __half* BC = (__half*)p; p += SZH * 2;
    int2* stg  = (int2*)p;  p += (long)NB2 * CAP2 * 8;      // 38.4 MB (>= NB1*CAP1*8 = 32 MB)
    int* rows1 = (int*)p; p += (long)NB1 * CAP1 * 4;        // 16 MB
    int* rowsA = (int*)p; p += (long)NB2 * CAP2 * 4;        // 19.2 MB
    int* rowsB = (int*)p; p += (long)NB2 * CAP2 * 4;        // 19.2 MB
    int2* offs1 = (int2*)p; p += (long)NN * 8;
    int2* offsA = (int2*)p; p += (long)MMn * 8;
    int2* offsB = (int2*)p; p += (long)MMn * 8;
    float* dinv1  = (float*)p; p += (long)NN * 4;
    float* dinv2  = (float*)p; p += (long)MMn * 4;
    float* dinv2r = (float*)p; p += (long)MMn * 4;
    int* gcur1 = (int*)p; p += 2048 * 4;
    int* gcurA = (int*)p; p += 4096 * 4;
    int* gcurB = (int*)p; p += 4096 * 4;
    int* freq = (int*)p; p += 1024 * 4;
    float* stats = (float*)p; p += 7 * 128 * 4;   // slots 0..6
    __half* Tn = (__half*)p; p += (long)NV * DD * 2;
    if ((size_t)(p - (char*)d_ws) > ws_size) return;

    // ---- zero freq + stats ----
    fill_i32_k<<<4, 256, 0, stream>>>(freq, 0, 1024);
    fill_f32_k<<<1, 256, 0, stream>>>(stats, 0.f, 7 * 128);

    // ---- emb-frequency histogram + table norm ----
    histx_k<<<cdiv_l(NN, 256), 256, 0, stream>>>(x, NN, freq);
    tabstats_k<<<1, 256, 0, stream>>>(emb, freq, NV, stats);
    tnorm_k<<<cdiv_l((long)NV * DD, 256), 256, 0, stream>>>(emb, stats, egw, egb, egm, Tn, NV);

    // ---- CSR build, atomic-light (g1, then g2 fwd, then g2 rev; stg reused serially) ----
    ginit_k<<<cdiv_l(NB1, 256), 256, 0, stream>>>(gcur1, NB1, CAP1);
    stage_one_k<<<NBLK, 256, 0, stream>>>(edge1 + NE1, edge1, NE1, gcur1, stg, NB1, CAP1);
    fill_one_k<CAP1><<<NB1, 256, 0, stream>>>(stg, gcur1, NN, rows1, offs1, dinv1);

    ginit_k<<<cdiv_l(NB2, 256), 256, 0, stream>>>(gcurA, NB2, CAP2);
    stage_one_k<<<NBLK, 256, 0, stream>>>(edge2 + NE2, edge2, NE2, gcurA, stg, NB2, CAP2);
    fill_one_k<CAP2><<<NB2, 256, 0, stream>>>(stg, gcurA, MMn, rowsA, offsA, dinv2);

    ginit_k<<<cdiv_l(NB2, 256), 256, 0, stream>>>(gcurB, NB2, CAP2);
    stage_one_k<<<NBLK, 256, 0, stream>>>(edge2, edge2 + NE2, NE2, gcurB, stg, NB2, CAP2);
    fill_one_k<CAP2><<<NB2, 256, 0, stream>>>(stg, gcurB, MMn, rowsB, offsB, dinv2r);

    // ---- conv1 l0: table-gather + mm -> BB, stats slot1 fused ----
    gcn_tab_fused_k<<<GGRID, 256, 0, stream>>>(Tn, x, offs1, rows1, dinv1, c1W, c1b, BB, stats + 128, NN);

    // ---- conv1 l1: gather(norm+relu) + mm -> BA, stats slot2 fused ----
    gcn_fused_k<2><<<GGRID, 256, 0, stream>>>(BB, offs1, rows1, dinv1,
        stats + 128, c1gw, c1gb, c1gm, (float)NN, c1W + 4096, c1b + 64, BA, stats + 256, NN);

    // ---- pair product (norm+relu fused on reads) -> BC ----
    pair_norm_mul_k<<<cdiv_l(MMn, 4), 256, 0, stream>>>(BA, pos1,
        stats + 256, c1gw + 64, c1gb + 64, c1gm + 64, BC);

    // ---- conv2 l0 (stats slots 3,4 fused) ----
    gcn_fused_k<0><<<GGRID, 256, 0, stream>>>(BC, offsA, rowsA, dinv2,
        stats, nullptr, nullptr, nullptr, 1.f, c2W, c2b, BB, stats + 384, MMn);
    gcn_fused_k<0><<<GGRID, 256, 0, stream>>>(BC, offsB, rowsB, dinv2r,
        stats, nullptr, nullptr, nullptr, 1.f, c2rW, c2rb, BA, stats + 512, MMn);
    dualadd_k<<<1024, 256, 0, stream>>>((const __half2*)BB, (const __half2*)BA,
        stats + 384, c2gw, c2gb, c2gm,
        stats + 512, c2rgw, c2rgb, c2rgm, (__half2*)BC);

    // ---- conv2 l1 (stats slots 5,6 fused) ----
    gcn_fused_k<0><<<GGRID, 256, 0, stream>>>(BC, offsA, rowsA, dinv2,
        stats, nullptr, nullptr, nullptr, 1.f, c2W + 4096, c2b + 64, BB, stats + 640, MMn);
    gcn_fused_k<0><<<GGRID, 256, 0, stream>>>(BC, offsB, rowsB, dinv2r,
        stats, nullptr, nullptr, nullptr, 1.f, c2rW + 4096, c2rb + 64, BA, stats + 768, MMn);

    // ---- final ----
    final_fused_k<<<cdiv_l(out_size, 4), 256, 0, stream>>>(BB, BA, pos2,
        stats + 640, c2gw + 64, c2gb + 64, c2gm + 64,
        stats + 768, c2rgw + 64, c2rgb + 64, c2rgm + 64,
        predW, predb, out, out_size);
}

// Round 8
// 1430.681 us; speedup vs baseline: 4.6711x; 1.2137x over previous
//
#include <hip/hip_runtime.h>
#include <hip/hip_fp16.h>

#define NN 100000      // nodes graph 1
#define MMn 200000     // nodes graph 2 (link nodes)
#define DD 64
#define NE1 3200000
#define NE2 3200000
#define SHB 6          // 64-node buckets
#define NB1 1563       // ceil(NN/64)
#define NB2 3125       // MMn/64
#define CAP1 2560      // g1 bucket capacity: mean 2048 + ~11 sigma
#define CAP2 1536      // g2 bucket capacity: mean 1024 + ~16 sigma
#define NBLK 256       // staging blocks (128 used only half the CUs)
#define GGRID 2048     // grid-stride blocks for gcn kernels

static inline int cdiv_l(long a, long b) { return (int)((a + b - 1) / b); }

// ================= small utility kernels =================
__global__ void fill_i32_k(int* p, int v, long n) {
    long i = (long)blockIdx.x * blockDim.x + threadIdx.x;
    long st = (long)gridDim.x * blockDim.x;
    for (; i < n; i += st) p[i] = v;
}
__global__ void fill_f32_k(float* p, float v, long n) {
    long i = (long)blockIdx.x * blockDim.x + threadIdx.x;
    long st = (long)gridDim.x * blockDim.x;
    for (; i < n; i += st) p[i] = v;
}
__global__ void ginit_k(int* gcur, int nb, int cap) {
    int b = blockIdx.x * blockDim.x + threadIdx.x;
    if (b < nb) gcur[b] = b * cap;
}
__global__ void histx_k(const int* __restrict__ x, int n, int* __restrict__ freq) {
    int i = blockIdx.x * blockDim.x + threadIdx.x;
    if (i < n) atomicAdd(&freq[x[i]], 1);
}

// ================= atomic-light bucketed staging (round-6, proven) =================
__global__ __launch_bounds__(256) void stage_one_k(
    const int* __restrict__ keys, const int* __restrict__ vals, int ne,
    int* __restrict__ gcur, int2* __restrict__ stg, int nb, int cap)
{
    __shared__ int lcnt[3200];
    __shared__ int lbase[3200];
    int tid = threadIdx.x;
    for (int b = tid; b < nb; b += 256) lcnt[b] = 0;
    __syncthreads();
    int chunk = (ne + (int)gridDim.x - 1) / (int)gridDim.x;
    int s = blockIdx.x * chunk, e = min(ne, s + chunk);
    for (int i = s + tid; i < e; i += 256) atomicAdd(&lcnt[keys[i] >> SHB], 1);
    __syncthreads();
    for (int b = tid; b < nb; b += 256) {
        int c = lcnt[b];
        lbase[b] = c ? atomicAdd(&gcur[b], c) : 0;
        lcnt[b] = 0;
    }
    __syncthreads();
    for (int i = s + tid; i < e; i += 256) {
        int k = keys[i];
        int bkt = k >> SHB;
        int idx = atomicAdd(&lcnt[bkt], 1);   // LDS cursor
        long pos = (long)lbase[bkt] + idx;
        if (pos < (long)(bkt + 1) * cap) stg[pos] = make_int2(vals[i], k);
    }
}

// ================= bucket-local CSR fill: zero global atomics =================
template <int CAPT>
__global__ __launch_bounds__(256) void fill_one_k(
    const int2* __restrict__ stg, const int* __restrict__ gcur, int n,
    int* __restrict__ rows, int2* __restrict__ offs, float* __restrict__ dinv)
{
    __shared__ int2 ent[CAPT];
    __shared__ int deg[64];
    __shared__ int sstart[65];
    int b = blockIdx.x, tid = threadIdx.x;
    long s = (long)b * CAPT;
    int cnt = min(gcur[b] - (int)s, CAPT);
    if (tid < 64) deg[tid] = 0;
    __syncthreads();
    for (int i = tid; i < cnt; i += 256) {
        int2 u = stg[s + i];
        ent[i] = u;
        atomicAdd(&deg[u.y & 63], 1);
    }
    __syncthreads();
    if (tid == 0) {
        int acc = 0;
#pragma unroll
        for (int j = 0; j < 64; ++j) { sstart[j] = acc; acc += deg[j]; }
        sstart[64] = acc;
    }
    __syncthreads();
    int node = (b << SHB) + tid;
    if (tid < 64 && node < n) {
        int st = sstart[tid], en = sstart[tid + 1];
        offs[node] = make_int2((int)s + st, (int)s + en);
        dinv[node] = rsqrtf((float)(en - st) + 1.0f);
    }
    if (tid < 64) deg[tid] = sstart[tid];  // reuse as cursor
    __syncthreads();
    for (int i = tid; i < cnt; i += 256) {
        int2 u = ent[i];
        int idx = atomicAdd(&deg[u.y & 63], 1);   // LDS cursor
        rows[s + idx] = u.x;
    }
}

// ================= GraphNorm coefficient (inline, per consumer) =================
__device__ __forceinline__ void gn_coef(const float* __restrict__ stats,
                                        const float* __restrict__ w, const float* __restrict__ b,
                                        const float* __restrict__ ms, float nrows, int d,
                                        float& sc, float& sh) {
    float mean = stats[d] / nrows;
    float ex2 = stats[64 + d] / nrows;
    float m = ms[d];
    float var = ex2 - mean * mean * (2.f * m - m * m);
    float is = rsqrtf(var + 1e-5f);
    sc = is * w[d];
    sh = b[d] - m * mean * sc;
}

// ================= embedding-table stats (frequency-weighted moments) =================
__global__ __launch_bounds__(256) void tabstats_k(const float* __restrict__ T, const int* __restrict__ freq,
                                                  int nv, float* __restrict__ stats) {
    __shared__ float sS[256], sQ[256];
    int tid = threadIdx.x; int d = tid & 63; int g = tid >> 6;
    float s = 0.f, q = 0.f;
    for (int v = g; v < nv; v += 4) {
        float f = (float)freq[v];
        float t = T[(long)v * DD + d];
        s += f * t; q += f * t * t;
    }
    sS[tid] = s; sQ[tid] = q; __syncthreads();
    if (tid < 128) { sS[tid] += sS[tid + 128]; sQ[tid] += sQ[tid + 128]; }
    __syncthreads();
    if (tid < 64) { stats[d] = sS[tid] + sS[tid + 64]; stats[64 + d] = sQ[tid] + sQ[tid + 64]; }
}

// ================= normalized fp16 embedding table =================
__global__ void tnorm_k(const float* __restrict__ T, const float* __restrict__ stats,
                        const float* __restrict__ w, const float* __restrict__ b,
                        const float* __restrict__ ms, __half* __restrict__ Tn, int nv) {
    int i = blockIdx.x * blockDim.x + threadIdx.x;
    if (i >= nv * DD) return;
    int d = i & 63;
    float sc, sh;
    gn_coef(stats, w, b, ms, (float)NN, d, sc, sh);
    Tn[i] = __float2half(fmaf(T[i], sc, sh));
}

// load W (row-major [k][d]) into LDS as float4 chunks: sW4[j*64+d] = W[4j..4j+3][d]
__device__ __forceinline__ void load_W4(const float* __restrict__ W, float4* sW4, int tid) {
    for (int idx = tid; idx < 1024; idx += 256) {
        int j = idx >> 6, dd = idx & 63;
        int k = j * 4;
        sW4[idx] = make_float4(W[k * 64 + dd], W[(k + 1) * 64 + dd],
                               W[(k + 2) * 64 + dd], W[(k + 3) * 64 + dd]);
    }
}

// ================= fused GCN layer: half2 gather + matmul + bias + fused stats =================
// Barrier-free main loop: sP slice is wave-private (in-wave DS ordering suffices).
// Lane l: dims (2q,2q+1), q=l&31; lane-groups 0/1 take even/odd edges; 4 edges in
// flight per group (8/wave). Matmul reads float4 operands: 32 LDS instr vs 128.
// NORM: 0 = raw input, 1 = affine (GN, no relu), 2 = affine + relu
template <int NORM>
__global__ __launch_bounds__(256) void gcn_fused_k(
    const __half* __restrict__ hsrc, const int2* __restrict__ offs,
    const int* __restrict__ rows, const float* __restrict__ dinv,
    const float* __restrict__ stats, const float* __restrict__ gw,
    const float* __restrict__ gb, const float* __restrict__ gms, float nprev,
    const float* __restrict__ W, const float* __restrict__ bias,
    __half* __restrict__ Z, float* __restrict__ ostats, int n)
{
    __shared__ float4 sW4[1024];
    __shared__ float sP[256];
    __shared__ float rs[256];
    int tid = threadIdx.x;
    load_W4(W, sW4, tid);
    int wr = tid >> 6, d = tid & 63;
    int q = tid & 31, grp = (tid >> 5) & 1;
    int d0 = q * 2;
    float sc0 = 1.f, sh0 = 0.f, sc1 = 1.f, sh1 = 0.f;
    if (NORM) {
        gn_coef(stats, gw, gb, gms, nprev, d0, sc0, sh0);
        gn_coef(stats, gw, gb, gms, nprev, d0 + 1, sc1, sh1);
    }
    float bd = bias[d];
    float sumz = 0.f, sumq = 0.f;
    const __half2* h2 = (const __half2*)hsrc;
    float2* sPw = (float2*)(sP + wr * 64);
    const float4* sPv = (const float4*)(sP + wr * 64);
    int ngrp = (n + 3) >> 2;
    __syncthreads();   // sW4 ready; no barriers inside the loop
    for (int g = blockIdx.x; g < ngrp; g += gridDim.x) {
        int node = g * 4 + wr;
        if (node < n) {
            int2 se = offs[node];
            int s = se.x, e = se.y;
            float dc = dinv[node];
            float a0 = 0.f, a1 = 0.f, b0 = 0.f, b1 = 0.f;
            float c0 = 0.f, c1 = 0.f, e0 = 0.f, e1 = 0.f;
            if (!grp) {
                __half2 u = h2[(long)node * 32 + q];
                float x0 = __low2float(u), x1 = __high2float(u);
                if (NORM) {
                    x0 = fmaf(x0, sc0, sh0); x1 = fmaf(x1, sc1, sh1);
                    if (NORM == 2) { x0 = fmaxf(x0, 0.f); x1 = fmaxf(x1, 0.f); }
                }
                a0 = x0 * dc; a1 = x1 * dc;
            }
            int i = s + grp;
            for (; i + 6 < e; i += 8) {
                int r0 = rows[i], r1 = rows[i + 2], r2 = rows[i + 4], r3 = rows[i + 6];
                float w0 = dinv[r0], w1 = dinv[r1], w2 = dinv[r2], w3 = dinv[r3];
                __half2 u0 = h2[(long)r0 * 32 + q];
                __half2 u1 = h2[(long)r1 * 32 + q];
                __half2 u2 = h2[(long)r2 * 32 + q];
                __half2 u3 = h2[(long)r3 * 32 + q];
                float x00 = __low2float(u0), x01 = __high2float(u0);
                float x10 = __low2float(u1), x11 = __high2float(u1);
                float x20 = __low2float(u2), x21 = __high2float(u2);
                float x30 = __low2float(u3), x31 = __high2float(u3);
                if (NORM) {
                    x00 = fmaf(x00, sc0, sh0); x01 = fmaf(x01, sc1, sh1);
                    x10 = fmaf(x10, sc0, sh0); x11 = fmaf(x11, sc1, sh1);
                    x20 = fmaf(x20, sc0, sh0); x21 = fmaf(x21, sc1, sh1);
                    x30 = fmaf(x30, sc0, sh0); x31 = fmaf(x31, sc1, sh1);
                    if (NORM == 2) {
                        x00 = fmaxf(x00, 0.f); x01 = fmaxf(x01, 0.f);
                        x10 = fmaxf(x10, 0.f); x11 = fmaxf(x11, 0.f);
                        x20 = fmaxf(x20, 0.f); x21 = fmaxf(x21, 0.f);
                        x30 = fmaxf(x30, 0.f); x31 = fmaxf(x31, 0.f);
                    }
                }
                a0 = fmaf(x00, w0, a0); a1 = fmaf(x01, w0, a1);
                b0 = fmaf(x10, w1, b0); b1 = fmaf(x11, w1, b1);
                c0 = fmaf(x20, w2, c0); c1 = fmaf(x21, w2, c1);
                e0 = fmaf(x30, w3, e0); e1 = fmaf(x31, w3, e1);
            }
            for (; i < e; i += 2) {
                int r = rows[i];
                float w0 = dinv[r];
                __half2 u = h2[(long)r * 32 + q];
                float x0 = __low2float(u), x1 = __high2float(u);
                if (NORM) {
                    x0 = fmaf(x0, sc0, sh0); x1 = fmaf(x1, sc1, sh1);
                    if (NORM == 2) { x0 = fmaxf(x0, 0.f); x1 = fmaxf(x1, 0.f); }
                }
                a0 = fmaf(x0, w0, a0); a1 = fmaf(x1, w0, a1);
            }
            a0 = (a0 + b0) + (c0 + e0);
            a1 = (a1 + b1) + (c1 + e1);
            a0 += __shfl_xor(a0, 32, 64);
            a1 += __shfl_xor(a1, 32, 64);
            if (!grp) sPw[q] = make_float2(a0 * dc, a1 * dc);  // wave-private slice
            float z = bd;
#pragma unroll
            for (int j = 0; j < 16; ++j) {
                float4 pv = sPv[j];                // broadcast b128 (in-wave ordered after write)
                float4 wv = sW4[j * 64 + d];       // coalesced b128
                z = fmaf(pv.x, wv.x, z); z = fmaf(pv.y, wv.y, z);
                z = fmaf(pv.z, wv.z, z); z = fmaf(pv.w, wv.w, z);
            }
            Z[(long)node * DD + d] = __float2half(z);
            sumz += z; sumq += z * z;
        }
    }
    // block stats reduction: 128 atomics/block
    __syncthreads();
    rs[tid] = sumz; __syncthreads();
    if (tid < 64) atomicAdd(&ostats[tid], rs[tid] + rs[tid + 64] + rs[tid + 128] + rs[tid + 192]);
    __syncthreads();
    rs[tid] = sumq; __syncthreads();
    if (tid < 64) atomicAdd(&ostats[64 + tid], rs[tid] + rs[tid + 64] + rs[tid + 128] + rs[tid + 192]);
}

// ================= conv1-l0: half2 gather from normalized fp16 table (L2-resident) =================
__global__ __launch_bounds__(256) void gcn_tab_fused_k(
    const __half* __restrict__ Tn, const int* __restrict__ xidx,
    const int2* __restrict__ offs, const int* __restrict__ rows,
    const float* __restrict__ dinv,
    const float* __restrict__ W, const float* __restrict__ bias,
    __half* __restrict__ Z, float* __restrict__ ostats, int n)
{
    __shared__ float4 sW4[1024];
    __shared__ float sP[256];
    __shared__ float rs[256];
    int tid = threadIdx.x;
    load_W4(W, sW4, tid);
    int wr = tid >> 6, d = tid & 63;
    int q = tid & 31, grp = (tid >> 5) & 1;
    float bd = bias[d];
    float sumz = 0.f, sumq = 0.f;
    const __half2* t2 = (const __half2*)Tn;
    float2* sPw = (float2*)(sP + wr * 64);
    const float4* sPv = (const float4*)(sP + wr * 64);
    int ngrp = (n + 3) >> 2;
    __syncthreads();
    for (int g = blockIdx.x; g < ngrp; g += gridDim.x) {
        int node = g * 4 + wr;
        if (node < n) {
            int2 se = offs[node];
            int s = se.x, e = se.y;
            float dc = dinv[node];
            float a0 = 0.f, a1 = 0.f, b0 = 0.f, b1 = 0.f;
            float c0 = 0.f, c1 = 0.f, e0 = 0.f, e1 = 0.f;
            if (!grp) {
                __half2 u = t2[(long)xidx[node] * 32 + q];
                a0 = __low2float(u) * dc; a1 = __high2float(u) * dc;
            }
            int i = s + grp;
            for (; i + 6 < e; i += 8) {
                int r0 = rows[i], r1 = rows[i + 2], r2 = rows[i + 4], r3 = rows[i + 6];
                float w0 = dinv[r0], w1 = dinv[r1], w2 = dinv[r2], w3 = dinv[r3];
                __half2 u0 = t2[(long)xidx[r0] * 32 + q];
                __half2 u1 = t2[(long)xidx[r1] * 32 + q];
                __half2 u2 = t2[(long)xidx[r2] * 32 + q];
                __half2 u3 = t2[(long)xidx[r3] * 32 + q];
                a0 = fmaf(__low2float(u0), w0, a0); a1 = fmaf(__high2float(u0), w0, a1);
                b0 = fmaf(__low2float(u1), w1, b0); b1 = fmaf(__high2float(u1), w1, b1);
                c0 = fmaf(__low2float(u2), w2, c0); c1 = fmaf(__high2float(u2), w2, c1);
                e0 = fmaf(__low2float(u3), w3, e0); e1 = fmaf(__high2float(u3), w3, e1);
            }
            for (; i < e; i += 2) {
                int r = rows[i];
                float w0 = dinv[r];
                __half2 u = t2[(long)xidx[r] * 32 + q];
                a0 = fmaf(__low2float(u), w0, a0); a1 = fmaf(__high2float(u), w0, a1);
            }
            a0 = (a0 + b0) + (c0 + e0);
            a1 = (a1 + b1) + (c1 + e1);
            a0 += __shfl_xor(a0, 32, 64);
            a1 += __shfl_xor(a1, 32, 64);
            if (!grp) sPw[q] = make_float2(a0 * dc, a1 * dc);
            float z = bd;
#pragma unroll
            for (int j = 0; j < 16; ++j) {
                float4 pv = sPv[j];
                float4 wv = sW4[j * 64 + d];
                z = fmaf(pv.x, wv.x, z); z = fmaf(pv.y, wv.y, z);
                z = fmaf(pv.z, wv.z, z); z = fmaf(pv.w, wv.w, z);
            }
            Z[(long)node * DD + d] = __float2half(z);
            sumz += z; sumq += z * z;
        }
    }
    __syncthreads();
    rs[tid] = sumz; __syncthreads();
    if (tid < 64) atomicAdd(&ostats[tid], rs[tid] + rs[tid + 64] + rs[tid + 128] + rs[tid + 192]);
    __syncthreads();
    rs[tid] = sumq; __syncthreads();
    if (tid < 64) atomicAdd(&ostats[64 + tid], rs[tid] + rs[tid + 64] + rs[tid + 128] + rs[tid + 192]);
}

// ================= link-pair product with fused GN+relu on reads =================
__global__ __launch_bounds__(256) void pair_norm_mul_k(
    const __half* __restrict__ Z2, const int* __restrict__ pos,
    const float* __restrict__ stats, const float* __restrict__ gw,
    const float* __restrict__ gb, const float* __restrict__ gms,
    __half* __restrict__ h2)
{
    int tid = threadIdx.x, wr = tid >> 6, d = tid & 63;
    int idx = blockIdx.x * 4 + wr;
    if (idx >= MMn) return;
    float sc, sh;
    gn_coef(stats, gw, gb, gms, (float)NN, d, sc, sh);
    int p0 = pos[2 * idx], p1 = pos[2 * idx + 1];
    float v0 = fmaxf(fmaf(__half2float(Z2[(long)p0 * DD + d]), sc, sh), 0.f);
    float v1 = fmaxf(fmaf(__half2float(Z2[(long)p1 * DD + d]), sc, sh), 0.f);
    h2[(long)idx * DD + d] = __float2half(v0 * v1);
}

// ================= dual-branch GN+relu+add =================
__global__ __launch_bounds__(256) void dualadd_k(
    const __half2* __restrict__ Za, const __half2* __restrict__ Zb,
    const float* __restrict__ stA, const float* __restrict__ wA, const float* __restrict__ bA, const float* __restrict__ msA,
    const float* __restrict__ stB, const float* __restrict__ wB, const float* __restrict__ bB, const float* __restrict__ msB,
    __half2* __restrict__ hout)
{
    const long nu = (long)MMn * 32;
    int tid = threadIdx.x;
    int d0 = (2 * tid) & 63;
    float scA0, shA0, scA1, shA1, scB0, shB0, scB1, shB1;
    gn_coef(stA, wA, bA, msA, (float)MMn, d0, scA0, shA0);
    gn_coef(stA, wA, bA, msA, (float)MMn, d0 + 1, scA1, shA1);
    gn_coef(stB, wB, bB, msB, (float)MMn, d0, scB0, shB0);
    gn_coef(stB, wB, bB, msB, (float)MMn, d0 + 1, scB1, shB1);
    for (long i = (long)blockIdx.x * 256 + tid; i < nu; i += (long)gridDim.x * 256) {
        __half2 ua = Za[i], ub = Zb[i];
        float a0 = __low2float(ua), a1 = __high2float(ua);
        float c0 = __low2float(ub), c1 = __high2float(ub);
        float o0 = fmaxf(fmaf(a0, scA0, shA0), 0.f) + fmaxf(fmaf(c0, scB0, shB0), 0.f);
        float o1 = fmaxf(fmaf(a1, scA1, shA1), 0.f) + fmaxf(fmaf(c1, scB1, shB1), 0.f);
        hout[i] = __halves2half2(__float2half(o0), __float2half(o1));
    }
}

// ================= final: dual GN+relu+add on reads, pair product, dot predW =================
__global__ __launch_bounds__(256) void final_fused_k(
    const __half* __restrict__ Za, const __half* __restrict__ Zb,
    const int* __restrict__ pos2,
    const float* __restrict__ stA, const float* __restrict__ wA, const float* __restrict__ bA, const float* __restrict__ msA,
    const float* __restrict__ stB, const float* __restrict__ wB, const float* __restrict__ bB, const float* __restrict__ msB,
    const float* __restrict__ pw, const float* __restrict__ pb,
    float* __restrict__ out, int nout)
{
    int tid = threadIdx.x, wr = tid >> 6, d = tid & 63;
    int i = blockIdx.x * 4 + wr;
    if (i >= nout) return;
    float scA, shA, scB, shB;
    gn_coef(stA, wA, bA, msA, (float)MMn, d, scA, shA);
    gn_coef(stB, wB, bB, msB, (float)MMn, d, scB, shB);
    int p0 = pos2[2 * i], p1 = pos2[2 * i + 1];
    float v0 = fmaxf(fmaf(__half2float(Za[(long)p0 * DD + d]), scA, shA), 0.f)
             + fmaxf(fmaf(__half2float(Zb[(long)p0 * DD + d]), scB, shB), 0.f);
    float v1 = fmaxf(fmaf(__half2float(Za[(long)p1 * DD + d]), scA, shA), 0.f)
             + fmaxf(fmaf(__half2float(Zb[(long)p1 * DD + d]), scB, shB), 0.f);
    float v = v0 * v1 * pw[d];
#pragma unroll
    for (int o = 32; o > 0; o >>= 1) v += __shfl_down(v, o, 64);
    if (d == 0) out[i] = v + pb[0];
}

extern "C" void kernel_launch(void* const* d_in, const int* in_sizes, int n_in,
                              void* d_out, int out_size, void* d_ws, size_t ws_size,
                              hipStream_t stream) {
    const int* x      = (const int*)d_in[0];
    const int* edge1  = (const int*)d_in[2];
    const int* edge2  = (const int*)d_in[3];
    const int* pos1   = (const int*)d_in[5];
    const int* pos2   = (const int*)d_in[6];
    const float* emb  = (const float*)d_in[7];
    const float* egw  = (const float*)d_in[8];
    const float* egb  = (const float*)d_in[9];
    const float* egm  = (const float*)d_in[10];
    const float* c1W  = (const float*)d_in[11];
    const float* c1b  = (const float*)d_in[12];
    const float* c1gw = (const float*)d_in[13];
    const float* c1gb = (const float*)d_in[14];
    const float* c1gm = (const float*)d_in[15];
    const float* c2W  = (const float*)d_in[16];
    const float* c2b  = (const float*)d_in[17];
    const float* c2gw = (const float*)d_in[18];
    const float* c2gb = (const float*)d_in[19];
    const float* c2gm = (const float*)d_in[20];
    const float* c2rW  = (const float*)d_in[21];
    const float* c2rb  = (const float*)d_in[22];
    const float* c2rgw = (const float*)d_in[23];
    const float* c2rgb = (const float*)d_in[24];
    const float* c2rgm = (const float*)d_in[25];
    const float* predW = (const float*)d_in[26];
    const float* predb = (const float*)d_in[27];
    float* out = (float*)d_out;
    const int NV = 1001;   // emb table rows (MAXX+1)

    // ---- workspace layout (~176 MB) ----
    char* p = (char*)d_ws;
    const long SZH = (long)MMn * DD;  // elements per fp16 node buffer
    __half* BA = (__half*)p; p += SZH * 2;
    __half* BB = (__half*)p; p += SZH * 2;
    __half* BC = (__half*)p; p += SZH * 2;
    int2* stg  = (int2*)p;  p += (long)NB2 * CAP2 * 8;      // 38.4 MB (>= NB1*CAP1*8 = 32 MB)
    int* rows1 = (int*)p; p += (long)NB1 * CAP1 * 4;        // 16 MB
    int* rowsA = (int*)p; p += (long)NB2 * CAP2 * 4;        // 19.2 MB
    int* rowsB = (int*)p; p += (long)NB2 * CAP2 * 4;        // 19.2 MB
    int2* offs1 = (int2*)p; p += (long)NN * 8;
    int2* offsA = (int2*)p; p += (long)MMn * 8;
    int2* offsB = (int2*)p; p += (long)MMn * 8;
    float* dinv1  = (float*)p; p += (long)NN * 4;
    float* dinv2  = (float*)p; p += (long)MMn * 4;
    float* dinv2r = (float*)p; p += (long)MMn * 4;
    int* gcur1 = (int*)p; p += 2048 * 4;
    int* gcurA = (int*)p; p += 4096 * 4;
    int* gcurB = (int*)p; p += 4096 * 4;
    int* freq = (int*)p; p += 1024 * 4;
    float* stats = (float*)p; p += 7 * 128 * 4;   // slots 0..6
    __half* Tn = (__half*)p; p += (long)NV * DD * 2;
    if ((size_t)(p - (char*)d_ws) > ws_size) return;

    // ---- zero freq + stats ----
    fill_i32_k<<<4, 256, 0, stream>>>(freq, 0, 1024);
    fill_f32_k<<<1, 256, 0, stream>>>(stats, 0.f, 7 * 128);

    // ---- emb-frequency histogram + table norm ----
    histx_k<<<cdiv_l(NN, 256), 256, 0, stream>>>(x, NN, freq);
    tabstats_k<<<1, 256, 0, stream>>>(emb, freq, NV, stats);
    tnorm_k<<<cdiv_l((long)NV * DD, 256), 256, 0, stream>>>(emb, stats, egw, egb, egm, Tn, NV);

    // ---- CSR build, atomic-light (g1, then g2 fwd, then g2 rev; stg reused serially) ----
    ginit_k<<<cdiv_l(NB1, 256), 256, 0, stream>>>(gcur1, NB1, CAP1);
    stage_one_k<<<NBLK, 256, 0, stream>>>(edge1 + NE1, edge1, NE1, gcur1, stg, NB1, CAP1);
    fill_one_k<CAP1><<<NB1, 256, 0, stream>>>(stg, gcur1, NN, rows1, offs1, dinv1);

    ginit_k<<<cdiv_l(NB2, 256), 256, 0, stream>>>(gcurA, NB2, CAP2);
    stage_one_k<<<NBLK, 256, 0, stream>>>(edge2 + NE2, edge2, NE2, gcurA, stg, NB2, CAP2);
    fill_one_k<CAP2><<<NB2, 256, 0, stream>>>(stg, gcurA, MMn, rowsA, offsA, dinv2);

    ginit_k<<<cdiv_l(NB2, 256), 256, 0, stream>>>(gcurB, NB2, CAP2);
    stage_one_k<<<NBLK, 256, 0, stream>>>(edge2, edge2 + NE2, NE2, gcurB, stg, NB2, CAP2);
    fill_one_k<CAP2><<<NB2, 256, 0, stream>>>(stg, gcurB, MMn, rowsB, offsB, dinv2r);

    // ---- conv1 l0: table-gather + mm -> BB, stats slot1 fused ----
    gcn_tab_fused_k<<<GGRID, 256, 0, stream>>>(Tn, x, offs1, rows1, dinv1, c1W, c1b, BB, stats + 128, NN);

    // ---- conv1 l1: gather(norm+relu) + mm -> BA, stats slot2 fused ----
    gcn_fused_k<2><<<GGRID, 256, 0, stream>>>(BB, offs1, rows1, dinv1,
        stats + 128, c1gw, c1gb, c1gm, (float)NN, c1W + 4096, c1b + 64, BA, stats + 256, NN);

    // ---- pair product (norm+relu fused on reads) -> BC ----
    pair_norm_mul_k<<<cdiv_l(MMn, 4), 256, 0, stream>>>(BA, pos1,
        stats + 256, c1gw + 64, c1gb + 64, c1gm + 64, BC);

    // ---- conv2 l0 (stats slots 3,4 fused) ----
    gcn_fused_k<0><<<GGRID, 256, 0, stream>>>(BC, offsA, rowsA, dinv2,
        stats, nullptr, nullptr, nullptr, 1.f, c2W, c2b, BB, stats + 384, MMn);
    gcn_fused_k<0><<<GGRID, 256, 0, stream>>>(BC, offsB, rowsB, dinv2r,
        stats, nullptr, nullptr, nullptr, 1.f, c2rW, c2rb, BA, stats + 512, MMn);
    dualadd_k<<<1024, 256, 0, stream>>>((const __half2*)BB, (const __half2*)BA,
        stats + 384, c2gw, c2gb, c2gm,
        stats + 512, c2rgw, c2rgb, c2rgm, (__half2*)BC);

    // ---- conv2 l1 (stats slots 5,6 fused) ----
    gcn_fused_k<0><<<GGRID, 256, 0, stream>>>(BC, offsA, rowsA, dinv2,
        stats, nullptr, nullptr, nullptr, 1.f, c2W + 4096, c2b + 64, BB, stats + 640, MMn);
    gcn_fused_k<0><<<GGRID, 256, 0, stream>>>(BC, offsB, rowsB, dinv2r,
        stats, nullptr, nullptr, nullptr, 1.f, c2rW + 4096, c2rb + 64, BA, stats + 768, MMn);

    // ---- final ----
    final_fused_k<<<cdiv_l(out_size, 4), 256, 0, stream>>>(BB, BA, pos2,
        stats + 640, c2gw + 64, c2gb + 64, c2gm + 64,
        stats + 768, c2rgw + 64, c2rgb + 64, c2rgm + 64,
        predW, predb, out, out_size);
}